// Round 12
// baseline (310.594 us; speedup 1.0000x reference)
//
#include <hip/hip_runtime.h>
#include <hip/hip_bf16.h>
#include <float.h>
#include <math.h>

// Problem constants
#define NB      4
#define QN      128
#define HID     512
#define NMEM    20000
#define NCHUNK  625
#define CHUNK   32
#define HEADS   8
#define DHEAD   64
#define TOPKK   8
#define NKV     1024
#define GLD     64       // G buffer ld (40 used cols)
#define LOGIT_SCALE 0.044194173824159216f  // 512^-0.5
#define W2LD    576
#define STROWS  520
#define LGLD    640
#define TLD     4096     // T ld: 8 heads x 512
#define ALD     520      // prepsum A_lds row stride (bf16), 1040B: 16B-aligned, ~2-way banks

typedef __attribute__((ext_vector_type(8))) short bf16x8;
typedef __attribute__((ext_vector_type(4))) short bf16x4;
typedef __attribute__((ext_vector_type(4))) float f32x4;

__device__ __forceinline__ short f2bf(float f){
  __hip_bfloat16 h = __float2bfloat16(f);
  return *reinterpret_cast<short*>(&h);
}
__device__ __forceinline__ float bf2f(unsigned short s){
  __hip_bfloat16 h;
  *reinterpret_cast<unsigned short*>(&h) = s;
  return __bfloat162float(h);
}
__device__ __forceinline__ bool mask_at(const void* m, int flag, long i){
  return flag ? (((const unsigned char*)m)[i] != 0)
              : (((const int*)m)[i] != 0);
}
__device__ __forceinline__ void gload16(const void* g, void* l){
  __builtin_amdgcn_global_load_lds((const __attribute__((address_space(1))) void*)g,
                                   (__attribute__((address_space(3))) void*)l, 16, 0, 0);
}

// ---------------- bigsetup: skwt + pos/flag + bfold + vker + wqk + qbf + PB(inline Wf) ----------------
// grid 710: [0,64) skwt; [64,128) pos/flag; [128] bfold; [129,134) vker;
//           [134,390) wqk; [390,646) qbf; [646,710) PB
__global__ __launch_bounds__(256) void bigsetup_kernel(const float* __restrict__ skw,
                                                       const void* __restrict__ mask,
                                                       const float* __restrict__ out_w,
                                                       const float* __restrict__ out_b,
                                                       const float* __restrict__ fc2_w,
                                                       const float* __restrict__ fc2_b,
                                                       const float* __restrict__ sq_w,
                                                       const float* __restrict__ sq_b,
                                                       const float* __restrict__ sk_b,
                                                       const float* __restrict__ q_w,
                                                       const float* __restrict__ kvw,
                                                       const float* __restrict__ queries,
                                                       float* __restrict__ skwT,
                                                       float* __restrict__ pos,
                                                       int* __restrict__ flagp,
                                                       float* __restrict__ bfold,
                                                       float* __restrict__ W2buf,
                                                       float* __restrict__ v2,
                                                       float* __restrict__ gbuf,
                                                       unsigned short* __restrict__ wqk,
                                                       unsigned short* __restrict__ qb,
                                                       unsigned short* __restrict__ PB){
  __shared__ float sm[12480];   // 49,920 B pool
  int sub = blockIdx.x;
  int t = threadIdx.x;
  if (sub < 64){
    float (*tile)[65] = (float(*)[65])sm;
    int c = t & 63, rbase = t >> 6;
    int e0 = (sub >> 3) * 64, j0 = (sub & 7) * 64;
#pragma unroll
    for (int j = 0; j < 16; ++j){
      int r = rbase + j * 4;
      tile[r][c] = skw[(long)(e0 + r) * 512 + j0 + c];
    }
    __syncthreads();
#pragma unroll
    for (int j = 0; j < 16; ++j){
      int rj = rbase + j * 4;
      skwT[(long)(j0 + rj) * 512 + e0 + c] = tile[c][rj];
    }
  } else if (sub < 128){
    int s = sub - 64;              // 0..63
    int cc = s >> 1;               // 0..31
    int d = (s & 1) * 256 + t;     // 0..511
    int j = (d < 256) ? d : d - 256;
    float invf = expf(-((2.0f * (float)j) / 512.0f) * 9.2103403719761836f);
    float arg = (float)(31 - cc) * invf;
    pos[cc * 512 + d] = (d < 256) ? sinf(arg) : cosf(arg);
    if (s == 0 && t == 0){
      const unsigned char* mb = (const unsigned char*)mask;
      *flagp = (mb[1] != 0) ? 1 : 0;
    }
  } else if (sub == 128){
    if (t < 5){
      float sb = 0.f;
      for (int k = 0; k < 512; ++k) sb += out_b[k] * fc2_w[k * 5 + t];
      bfold[t] = sb + fc2_b[t];
    }
  } else if (sub < 134){
    int s = sub - 129;             // 0..4
    if (s < 2){
      int d = s * 256 + t;
      float acc = 0.f;
      for (int j = 0; j < 512; ++j) acc += sq_w[(long)d * 512 + j] * sk_b[j];
      W2buf[(long)d * W2LD + 512] = acc;
      for (int cc = 513; cc < W2LD; ++cc) W2buf[(long)d * W2LD + cc] = 0.f;
    } else if (s < 4){
      int e = (s - 2) * 256 + t;
      float acc = 0.f;
      for (int j = 0; j < 512; ++j) acc += skw[(long)e * 512 + j] * sq_b[j];
      v2[e] = acc;
    } else {
      __shared__ float g[256];
      g[t] = sq_b[t] * sk_b[t] + sq_b[t + 256] * sk_b[t + 256];
      __syncthreads();
      for (int d = 128; d >= 1; d >>= 1){
        if (t < d) g[t] += g[t + d];
        __syncthreads();
      }
      if (t == 0) gbuf[0] = g[0];
    }
  } else if (sub < 390){
    // wqk: W_qk[h*512+d'][d] = 0.125 * sum_e kv_w[d'][h*64+e]*q_w[d][h*64+e]
    int bx = sub - 134;
    int h = bx >> 5, rem2 = bx & 31, dp = rem2 >> 2, dd = rem2 & 3;
    int dpr0 = dp * 64, dd0 = dd * 128;
    float (*Akv)[65] = (float(*)[65])sm;
    float (*Bq)[65]  = (float(*)[65])(sm + 64 * 65);
    for (int idx = t; idx < 64 * 64; idx += 256){
      int r = idx >> 6, e = idx & 63;
      Akv[r][e] = kvw[(long)(dpr0 + r) * NKV + h * 64 + e];
    }
    for (int idx = t; idx < 128 * 64; idx += 256){
      int r = idx >> 6, e = idx & 63;
      Bq[r][e] = q_w[(long)(dd0 + r) * 512 + h * 64 + e];
    }
    __syncthreads();
    int ty = t >> 4, tx = t & 15;
    float acc[4][8] = {};
    for (int e = 0; e < 64; ++e){
      float a0 = Akv[ty * 4 + 0][e], a1 = Akv[ty * 4 + 1][e];
      float a2 = Akv[ty * 4 + 2][e], a3 = Akv[ty * 4 + 3][e];
      float b[8];
#pragma unroll
      for (int v = 0; v < 8; ++v) b[v] = Bq[tx * 8 + v][e];
#pragma unroll
      for (int v = 0; v < 8; ++v){
        acc[0][v] += a0 * b[v];
        acc[1][v] += a1 * b[v];
        acc[2][v] += a2 * b[v];
        acc[3][v] += a3 * b[v];
      }
    }
#pragma unroll
    for (int u = 0; u < 4; ++u)
#pragma unroll
      for (int v = 0; v < 8; ++v)
        wqk[(long)(h * 512 + dpr0 + ty * 4 + u) * 512 + dd0 + tx * 8 + v] =
            (unsigned short)f2bf(acc[u][v] * 0.125f);
  } else if (sub < 646){
    long idx = (long)(sub - 390) * 256 + t;
    float4 v = *(const float4*)(queries + idx * 4);
    ushort4 o;
    o.x = (unsigned short)f2bf(v.x);
    o.y = (unsigned short)f2bf(v.y);
    o.z = (unsigned short)f2bf(v.z);
    o.w = (unsigned short)f2bf(v.w);
    *(ushort4*)(qb + idx * 4) = o;
  } else {
    // PB rows: row<40 => P[d][hj] via inline Wf column; else zero
    int row = sub - 646;           // 0..63
    if (row < 40){
      int h = row / 5, j = row - h * 5;
      __shared__ float wfc[64];
      if (t < 64){
        const float* owr = out_w + (long)(h * 64 + t) * 512;
        float s = 0.f;
        for (int k = 0; k < 512; ++k) s += owr[k] * fc2_w[k * 5 + j];
        wfc[t] = s;
      }
      __syncthreads();
      for (int d = t; d < 512; d += 256){
        const float* kr = kvw + (long)d * NKV + 512 + h * 64;
        float s = 0.f;
#pragma unroll
        for (int e = 0; e < 64; ++e) s += kr[e] * wfc[e];
        PB[(long)row * 512 + d] = (unsigned short)f2bf(s);
      }
    } else {
      for (int d = t; d < 512; d += 256) PB[(long)row * 512 + d] = 0;
    }
  }
}

// ---------------- main: [0,2500) prepsum+G ; [2500,2628) tgemm ; [2628,2884) W2 gemm ----------------
__global__ __launch_bounds__(512) void main_kernel(const float* __restrict__ memories,
                                                   const float* __restrict__ pos,
                                                   const void* __restrict__ mask,
                                                   const int* __restrict__ flagp,
                                                   const unsigned short* __restrict__ PB,
                                                   float* __restrict__ summ,
                                                   float* __restrict__ chunkden,
                                                   unsigned short* __restrict__ g_all,
                                                   const unsigned short* __restrict__ Aq,
                                                   const unsigned short* __restrict__ Bw,
                                                   float* __restrict__ T,
                                                   const float* __restrict__ sq_w,
                                                   const float* __restrict__ skwT,
                                                   float* __restrict__ W2buf){
  __shared__ char pool[52224];
  int blk = blockIdx.x;
  int t = threadIdx.x;
  int lane = t & 63, wid = t >> 6;
  int lr = lane & 15, lg = lane >> 4;

  if (blk < 2500){
    // ===== prepsum + fused G-GEMM, one chunk per block =====
    int b = blk / NCHUNK, n = blk - b * NCHUNK;
    unsigned short* A_lds = (unsigned short*)pool;              // 32*520*2 = 33,280
    float (*red)[9] = (float(*)[9])(pool + 33280);              // 512*9*4 = 18,432
    long mbase = (long)b * NMEM + (long)n * CHUNK;
    int flag = *flagp;
    bool mybit = mask_at(mask, flag, mbase + (t & 31));
    unsigned int m32 = (unsigned int)__ballot(mybit);
    float den = (float)__popc(m32);
    int rh = t >> 6;               // 0..7
    int c8 = t & 63;               // 8-elem col group
    const float* base = memories + mbase * HID + c8 * 8;
    const float* pbase = pos + c8 * 8;
    float4 va[4], vb[4], pa[4], pb4[4];
#pragma unroll
    for (int j = 0; j < 4; ++j){
      va[j] = *(const float4*)(base + (long)(rh + 8 * j) * HID);
      vb[j] = *(const float4*)(base + (long)(rh + 8 * j) * HID + 4);
    }
#pragma unroll
    for (int j = 0; j < 4; ++j){
      pa[j]  = *(const float4*)(pbase + (rh + 8 * j) * HID);
      pb4[j] = *(const float4*)(pbase + (rh + 8 * j) * HID + 4);
    }
#pragma unroll
    for (int j = 0; j < 4; ++j){
      ushort4 lo, hi;
      lo.x = (unsigned short)f2bf(va[j].x + pa[j].x);
      lo.y = (unsigned short)f2bf(va[j].y + pa[j].y);
      lo.z = (unsigned short)f2bf(va[j].z + pa[j].z);
      lo.w = (unsigned short)f2bf(va[j].w + pa[j].w);
      hi.x = (unsigned short)f2bf(vb[j].x + pb4[j].x);
      hi.y = (unsigned short)f2bf(vb[j].y + pb4[j].y);
      hi.z = (unsigned short)f2bf(vb[j].z + pb4[j].z);
      hi.w = (unsigned short)f2bf(vb[j].w + pb4[j].w);
      unsigned short* dst = A_lds + (long)(rh + 8 * j) * ALD + c8 * 8;
      *(ushort4*)dst = lo;
      *(ushort4*)(dst + 4) = hi;
    }
    float acc8[8] = {};
#pragma unroll
    for (int j = 0; j < 4; ++j){
      if (m32 & (1u << (rh + 8 * j))){
        acc8[0] += va[j].x; acc8[1] += va[j].y; acc8[2] += va[j].z; acc8[3] += va[j].w;
        acc8[4] += vb[j].x; acc8[5] += vb[j].y; acc8[6] += vb[j].z; acc8[7] += vb[j].w;
      }
    }
#pragma unroll
    for (int k = 0; k < 8; ++k) red[t][k] = acc8[k];
    __syncthreads();
    if (rh == 0){
      float s[8] = {};
      for (int g = 0; g < 8; ++g)
#pragma unroll
        for (int k = 0; k < 8; ++k) s[k] += red[g * 64 + c8][k];
      float dv = den + 1e-5f;
      float4 s0 = {s[0] / dv, s[1] / dv, s[2] / dv, s[3] / dv};
      float4 s1 = {s[4] / dv, s[5] / dv, s[6] / dv, s[7] / dv};
      float* srow = summ + ((long)b * NCHUNK + n) * 512 + c8 * 8;
      *(float4*)srow = s0;
      *(float4*)(srow + 4) = s1;
      if (t == 0) chunkden[b * NCHUNK + n] = den;
    }
    // fused G: 6 waves, each one 16x16 tile of A[32x512] @ PB^T[512x48]
    if (wid < 6){
      int mt = wid / 3, nt = wid - mt * 3;
      f32x4 acc4 = (f32x4)0.f;
#pragma unroll 1
      for (int k0 = 0; k0 < 512; k0 += 32){
        bf16x8 af = *(const bf16x8*)(A_lds + (long)(mt * 16 + lr) * ALD + k0 + lg * 8);
        bf16x8 bv = *(const bf16x8*)(PB + (long)(nt * 16 + lr) * 512 + k0 + lg * 8);
        acc4 = __builtin_amdgcn_mfma_f32_16x16x32_bf16(af, bv, acc4, 0, 0, 0);
      }
      int col = nt * 16 + lr;
      if (col < 40){
        unsigned short* gout = g_all + (size_t)b * NMEM * GLD;
#pragma unroll
        for (int rr = 0; rr < 4; ++rr){
          int row = n * CHUNK + mt * 16 + lg * 4 + rr;
          gout[(long)row * GLD + col] = (unsigned short)f2bf(acc4[rr]);
        }
      }
    }
  } else if (blk < 2628){
    // ===== tgemm: T = qbf @ wqk^T (f32 out), 128x128 tile, 8 waves =====
    int L2 = blk - 2500;
    int panel = L2 >> 5, nb = L2 & 31;
    int m0 = panel << 7, n0 = nb << 7;
    unsigned short* As[2] = { (unsigned short*)pool, (unsigned short*)(pool + 8192) };
    unsigned short* Bs[2] = { (unsigned short*)(pool + 16384), (unsigned short*)(pool + 24576) };
    int srow = t >> 2, scol = (t & 3) * 8;
    int wr = wid >> 2, wc = wid & 3;
    const unsigned short* gA = Aq + (long)(m0 + srow) * 512 + scol;
    const unsigned short* gB = Bw + (long)(n0 + srow) * 512 + scol;
    int lofs = srow * 32 + scol;

    f32x4 acc[4][2];
#pragma unroll
    for (int i = 0; i < 4; ++i){ acc[i][0] = (f32x4)0.f; acc[i][1] = (f32x4)0.f; }

#define TSTAGE(B, K0) { gload16(gA + (K0), &As[B][lofs]); gload16(gB + (K0), &Bs[B][lofs]); }
#define TCOMPUTE(B) { bf16x8 af[4], bfv[2]; \
  _Pragma("unroll") for (int mi = 0; mi < 4; ++mi) af[mi]  = *(const bf16x8*)&As[B][(wr * 64 + mi * 16 + lr) * 32 + lg * 8]; \
  _Pragma("unroll") for (int ni = 0; ni < 2; ++ni) bfv[ni] = *(const bf16x8*)&Bs[B][(wc * 32 + ni * 16 + lr) * 32 + lg * 8]; \
  _Pragma("unroll") for (int mi = 0; mi < 4; ++mi) \
    _Pragma("unroll") for (int ni = 0; ni < 2; ++ni) \
      acc[mi][ni] = __builtin_amdgcn_mfma_f32_16x16x32_bf16(af[mi], bfv[ni], acc[mi][ni], 0, 0, 0); }

    TSTAGE(0, 0);
    __syncthreads();
#pragma unroll 1
    for (int tt = 0; tt < 16; tt += 2){
      if (tt + 1 < 16) TSTAGE(1, (tt + 1) * 32);
      TCOMPUTE(0);
      __syncthreads();
      if (tt + 2 < 16) TSTAGE(0, (tt + 2) * 32);
      TCOMPUTE(1);
      __syncthreads();
    }
#undef TSTAGE
#undef TCOMPUTE

#pragma unroll
    for (int mi = 0; mi < 4; ++mi)
#pragma unroll
      for (int ni = 0; ni < 2; ++ni)
#pragma unroll
        for (int rr = 0; rr < 4; ++rr){
          int gr = m0 + wr * 64 + mi * 16 + lg * 4 + rr;
          int gn = n0 + wc * 32 + ni * 16 + lr;
          T[(long)gr * TLD + gn] = acc[mi][ni][rr];
        }
  } else {
    // ===== W2 = sq_w @ skwT (f32), 2 rows/wave, 8 waves => 16 rows/block =====
    int bx2 = blk - 2628;           // 0..255
    int rt = bx2 & 31, nt2 = bx2 >> 5;
    int r0 = rt * 16 + wid * 2;
    int nn = nt2 * 64 + lane;
    const float* a0 = sq_w + (long)r0 * 512;
    const float* bp = skwT + nn;
    float acc0 = 0.f, acc1 = 0.f;
#pragma unroll 4
    for (int k = 0; k < 512; k += 4){
      float b0 = bp[(long)k * 512];
      float b1 = bp[(long)(k + 1) * 512];
      float b2 = bp[(long)(k + 2) * 512];
      float b3 = bp[(long)(k + 3) * 512];
      float4 a;
      a = *(const float4*)(a0 + k);
      acc0 += a.x * b0 + a.y * b1 + a.z * b2 + a.w * b3;
      a = *(const float4*)(a0 + 512 + k);
      acc1 += a.x * b0 + a.y * b1 + a.z * b2 + a.w * b3;
    }
    W2buf[(long)r0 * W2LD + nn]       = acc0;
    W2buf[(long)(r0 + 1) * W2LD + nn] = acc1;
  }
}

// ---------------- ustb: blocks [0,576) u_ext (2 rows/wave); [576,1525) stbeta ----------------
__global__ __launch_bounds__(256) void ustb_kernel(const float* __restrict__ queries,
                                                   const float* __restrict__ W2buf,
                                                   float* __restrict__ u_ext,
                                                   const float* __restrict__ summ,
                                                   const float* __restrict__ v2,
                                                   const float* __restrict__ gbuf,
                                                   float* __restrict__ summText,
                                                   float* __restrict__ betag){
  int blk = blockIdx.x;
  int t = threadIdx.x;
  if (blk < 576){
    int ax = blk & 63, ay = blk >> 6;
    int lane = t & 63, w = t >> 6;
    int r0 = ax * 8 + w * 2;
    int n  = ay * 64 + lane;
    const float* a0 = queries + (long)r0 * 512;
    const float* bp = W2buf + n;
    float acc0 = 0.f, acc1 = 0.f;
#pragma unroll 4
    for (int k = 0; k < 512; k += 4){
      float b0 = bp[(long)k * W2LD];
      float b1 = bp[(long)(k + 1) * W2LD];
      float b2 = bp[(long)(k + 2) * W2LD];
      float b3 = bp[(long)(k + 3) * W2LD];
      float4 a;
      a = *(const float4*)(a0 + k);
      acc0 += a.x * b0 + a.y * b1 + a.z * b2 + a.w * b3;
      a = *(const float4*)(a0 + 512 + k);
      acc1 += a.x * b0 + a.y * b1 + a.z * b2 + a.w * b3;
    }
    u_ext[(long)r0 * W2LD + n]       = acc0;
    u_ext[(long)(r0 + 1) * W2LD + n] = acc1;
  } else if (blk < 896){
    __shared__ float tile[64][65];
    int b2 = blk - 576;
    int b = b2 / 80; int rem = b2 % 80;
    int n0 = (rem / 8) * 64, e0 = (rem % 8) * 64;
    int c = t & 63, rbase = t >> 6;
#pragma unroll
    for (int j = 0; j < 16; ++j){
      int r = rbase + j * 4;
      int n = n0 + r;
      tile[r][c] = (n < NCHUNK) ? summ[((long)b * NCHUNK + n) * 512 + e0 + c] : 0.f;
    }
    __syncthreads();
#pragma unroll
    for (int j = 0; j < 16; ++j){
      int re = rbase + j * 4;
      summText[(long)b * STROWS * LGLD + (long)(e0 + re) * LGLD + n0 + c] = tile[c][re];
    }
  } else if (blk < 900){
    int b = blk - 896;
    for (int idx = t; idx < 8 * LGLD; idx += 256){
      int e = idx / LGLD, n = idx - e * LGLD;
      summText[(long)b * STROWS * LGLD + (long)(512 + e) * LGLD + n] = (e == 0) ? 1.f : 0.f;
    }
  } else {
    int bb = blk - 900;
    int w = t >> 6, lane = t & 63;
    int row = bb * 4 + w;
    const float* r = summ + (long)row * 512;
    float s = 0.f;
#pragma unroll
    for (int c = 0; c < 8; ++c) s += r[lane + 64 * c] * v2[lane + 64 * c];
    for (int d = 32; d >= 1; d >>= 1) s += __shfl_xor(s, d, 64);
    if (lane == 0){
      int b = row / NCHUNK, n = row % NCHUNK;
      betag[b * LGLD + n] = s + gbuf[0];
    }
  }
}

// ---------------- logits (NN form): 2 rows/wave, grid (16,10,NB) ----------------
__global__ __launch_bounds__(256) void logits_nn(const float* __restrict__ u_ext,
                                                 const float* __restrict__ summText,
                                                 const float* __restrict__ betag,
                                                 const float* __restrict__ chunkden,
                                                 float* __restrict__ logits){
  int b = blockIdx.z;
  int tid = threadIdx.x;
  int lane = tid & 63, w = tid >> 6;
  int r0 = blockIdx.x * 8 + w * 2;
  int n  = blockIdx.y * 64 + lane;
  const float* a0 = u_ext + ((long)b * QN + r0) * W2LD;
  const float* bp = summText + (long)b * STROWS * LGLD + n;
  float acc0 = 0.f, acc1 = 0.f;
#pragma unroll 4
  for (int k = 0; k < STROWS; k += 4){
    float b0 = bp[(long)k * LGLD];
    float b1 = bp[(long)(k + 1) * LGLD];
    float b2 = bp[(long)(k + 2) * LGLD];
    float b3 = bp[(long)(k + 3) * LGLD];
    float4 a;
    a = *(const float4*)(a0 + k);
    acc0 += a.x * b0 + a.y * b1 + a.z * b2 + a.w * b3;
    a = *(const float4*)(a0 + W2LD + k);
    acc1 += a.x * b0 + a.y * b1 + a.z * b2 + a.w * b3;
  }
  if (n < NCHUNK){
    float bet = betag[b * LGLD + n];
    bool dead = (chunkden[b * NCHUNK + n] <= 0.f);
    float v0 = (acc0 + bet) * LOGIT_SCALE;
    float v1 = (acc1 + bet) * LOGIT_SCALE;
    if (dead){ v0 = v1 = -FLT_MAX; }
    long base = ((long)b * QN + r0) * LGLD + n;
    logits[base]        = v0;
    logits[base + LGLD] = v1;
  }
}

// ---------------- top-8 + softmax weights, 4 waves per (b,i) row ----------------
__global__ __launch_bounds__(256) void topk_kernel(const float* __restrict__ logits,
                                                   int* __restrict__ topi_out,
                                                   float* __restrict__ wts_out){
  int row = blockIdx.x;
  __shared__ float lds[NCHUNK];
  __shared__ float wv[4];
  __shared__ int   wi[4];
  __shared__ float topv[TOPKK];
  __shared__ int   topi[TOPKK];
  int t = threadIdx.x;
  int lane = t & 63, w = t >> 6;
  for (int idx = t; idx < NCHUNK; idx += 256) lds[idx] = logits[(long)row * LGLD + idx];
  __syncthreads();
  for (int it = 0; it < TOPKK; ++it){
    float bv = -INFINITY; int bi = 0x7fffffff;
    for (int idx = t; idx < NCHUNK; idx += 256){
      float v = lds[idx];
      if (v > bv){ bv = v; bi = idx; }
    }
    for (int d = 32; d >= 1; d >>= 1){
      float ov = __shfl_xor(bv, d, 64);
      int   oi = __shfl_xor(bi, d, 64);
      if (ov > bv || (ov == bv && oi < bi)){ bv = ov; bi = oi; }
    }
    if (lane == 0){ wv[w] = bv; wi[w] = bi; }
    __syncthreads();
    if (t == 0){
      float fb = wv[0]; int fi = wi[0];
      for (int j = 1; j < 4; ++j){
        if (wv[j] > fb || (wv[j] == fb && wi[j] < fi)){ fb = wv[j]; fi = wi[j]; }
      }
      topv[it] = fb; topi[it] = fi; lds[fi] = -INFINITY;
    }
    __syncthreads();
  }
  if (t == 0){
    float m = topv[0];
    for (int r = 1; r < TOPKK; ++r) m = fmaxf(m, topv[r]);
    float e[TOPKK], s = 0.f;
    for (int r = 0; r < TOPKK; ++r){ e[r] = expf(topv[r] - m); s += e[r]; }
    for (int r = 0; r < TOPKK; ++r){
      wts_out[(long)row * TOPKK + r] = e[r] / s;
      topi_out[(long)row * TOPKK + r] = topi[r];
    }
  }
}

// ---------------- attention: A staged from memories+pos (L3-hot), sim = T.A, G-fold out ----------------
#define ALDP 516   // attn A_lds row stride (bf16): 8B-aligned, 2-way-free for sim reads
__global__ __launch_bounds__(256) void attn5_kernel(const float* __restrict__ T,
                                                    const float* __restrict__ memories,
                                                    const float* __restrict__ pos,
                                                    const unsigned short* __restrict__ g_all,
                                                    const int* __restrict__ topidx,
                                                    const float* __restrict__ wts,
                                                    const void* __restrict__ mask,
                                                    const int* __restrict__ flagp,
                                                    float* __restrict__ osc5){
  int bx = blockIdx.x;
  int bb = bx >> 10, rem = bx & 1023;
  int i = rem >> 3, k = rem & 7;
  const unsigned short* gb = g_all + (size_t)bb * NMEM * GLD;
  int t = threadIdx.x;
  __shared__ unsigned short A_lds[32 * ALDP];
  __shared__ float T_lds[TLD];
  __shared__ float red[4][5];
  int flag = *flagp;
  long sel = ((long)(bb * QN + i)) * TOPKK + k;
  int chunk = topidx[sel];
  float w8 = wts[sel];
  const float* Trow = T + (long)(bb * QN + i) * TLD;
  for (int idx = t; idx < 1024; idx += 256)
    *(float4*)&T_lds[idx * 4] = *(const float4*)&Trow[idx * 4];
  {
    int r = t >> 3, cb = (t & 7) * 64;
    const float* src = memories + ((long)bb * NMEM + (long)chunk * CHUNK + r) * HID + cb;
    const float* ps  = pos + r * HID + cb;
    unsigned short* dst = &A_lds[r * ALDP + cb];
#pragma unroll
    for (int j = 0; j < 8; ++j){
      float4 m0 = *(const float4*)(src + j * 8);
      float4 m1 = *(const float4*)(src + j * 8 + 4);
      float4 p0 = *(const float4*)(ps + j * 8);
      float4 p1 = *(const float4*)(ps + j * 8 + 4);
      ushort4 lo, hi;
      lo.x = (unsigned short)f2bf(m0.x + p0.x);
      lo.y = (unsigned short)f2bf(m0.y + p0.y);
      lo.z = (unsigned short)f2bf(m0.z + p0.z);
      lo.w = (unsigned short)f2bf(m0.w + p0.w);
      hi.x = (unsigned short)f2bf(m1.x + p1.x);
      hi.y = (unsigned short)f2bf(m1.y + p1.y);
      hi.z = (unsigned short)f2bf(m1.z + p1.z);
      hi.w = (unsigned short)f2bf(m1.w + p1.w);
      *(ushort4*)(dst + j * 8)     = lo;
      *(ushort4*)(dst + j * 8 + 4) = hi;
    }
  }
  __syncthreads();
  int h = t >> 5, c = t & 31;
  const unsigned short* arow = &A_lds[c * ALDP];
  const float* tp = &T_lds[h * 512];
  float s = 0.f;
#pragma unroll 4
  for (int e8 = 0; e8 < 64; ++e8){
    bf16x4 alo = *(const bf16x4*)(arow + e8 * 8);
    bf16x4 ahi = *(const bf16x4*)(arow + e8 * 8 + 4);
    float4 ta = *(const float4*)(tp + e8 * 8);
    float4 tb = *(const float4*)(tp + e8 * 8 + 4);
    s += bf2f((unsigned short)alo[0]) * ta.x + bf2f((unsigned short)alo[1]) * ta.y
       + bf2f((unsigned short)alo[2]) * ta.z + bf2f((unsigned short)alo[3]) * ta.w
       + bf2f((unsigned short)ahi[0]) * tb.x + bf2f((unsigned short)ahi[1]) * tb.y
       + bf2f((unsigned short)ahi[2]) * tb.z + bf2f((unsigned short)ahi[3]) * tb.w;
  }
  bool mv = mask_at(mask, flag, (long)bb * NMEM + (long)chunk * CHUNK + c);
  if (!mv) s = -FLT_MAX;
  float m = s;
  for (int d = 16; d >= 1; d >>= 1) m = fmaxf(m, __shfl_xor(m, d, 32));
  float p = expf(s - m);
  float su = p;
  for (int d = 16; d >= 1; d >>= 1) su += __shfl_xor(su, d, 32);
  float att = p / su;
  const unsigned short* grow = gb + (long)(chunk * CHUNK + c) * GLD + h * 5;
  float p0 = att * bf2f(grow[0]);
  float p1 = att * bf2f(grow[1]);
  float p2 = att * bf2f(grow[2]);
  float p3 = att * bf2f(grow[3]);
  float p4 = att * bf2f(grow[4]);
#pragma unroll
  for (int d = 32; d >= 1; d >>= 1){
    p0 += __shfl_xor(p0, d, 64);
    p1 += __shfl_xor(p1, d, 64);
    p2 += __shfl_xor(p2, d, 64);
    p3 += __shfl_xor(p3, d, 64);
    p4 += __shfl_xor(p4, d, 64);
  }
  int w = t >> 6, lane = t & 63;
  if (lane == 0){
    red[w][0] = p0; red[w][1] = p1; red[w][2] = p2; red[w][3] = p3; red[w][4] = p4;
  }
  __syncthreads();
  if (t < 5){
    float tot = red[0][t] + red[1][t] + red[2][t] + red[3][t];
    osc5[sel * 8 + t] = w8 * tot;
  }
}

// ---------------- final5 ----------------
__global__ __launch_bounds__(64) void final5_kernel(const float* __restrict__ osc5,
                                                    const float* __restrict__ bfold,
                                                    float* __restrict__ out){
  int bi = blockIdx.x;
  int t = threadIdx.x;
  if (t < 5){
    float a = bfold[t];
#pragma unroll
    for (int k = 0; k < TOPKK; ++k) a += osc5[((long)bi * TOPKK + k) * 8 + t];
    out[bi * 5 + t] = a;
  }
}

extern "C" void kernel_launch(void* const* d_in, const int* in_sizes, int n_in,
                              void* d_out, int out_size, void* d_ws, size_t ws_size,
                              hipStream_t stream) {
  const float* queries  = (const float*)d_in[1];
  const float* memories = (const float*)d_in[2];
  const void*  mask     = d_in[3];
  const float* sq_w = (const float*)d_in[10];
  const float* sq_b = (const float*)d_in[11];
  const float* sk_w = (const float*)d_in[12];
  const float* sk_b = (const float*)d_in[13];
  const float* q_w  = (const float*)d_in[14];
  const float* kv_w = (const float*)d_in[15];
  const float* out_w = (const float*)d_in[16];
  const float* out_b = (const float*)d_in[17];
  const float* fc2_w = (const float*)d_in[18];
  const float* fc2_b = (const float*)d_in[19];
  float* out = (float*)d_out;

  char* ws = (char*)d_ws;
  size_t off = 0;
  auto alloc = [&](size_t bytes){ size_t o = off; off += (bytes + 511) & ~(size_t)511; return o; };
  size_t o_sum  = alloc(5120000);
  size_t o_den  = alloc(10240);
  size_t o_pos  = alloc(65536);
  size_t o_bf   = alloc(512);
  size_t o_ti   = alloc(16384);
  size_t o_wt   = alloc(16384);
  size_t o_flag = alloc(512);
  size_t o_w2   = alloc(1179648);
  size_t o_uex  = alloc(1179648);
  size_t o_st   = alloc(5324800);
  size_t o_bg   = alloc(10240);
  size_t o_v2   = alloc(2048);
  size_t o_gm   = alloc(512);
  size_t o_lg   = alloc(1310720);
  size_t o_osc5 = alloc(131072);
  size_t o_skt  = alloc(1048576);
  size_t o_qbf  = alloc(524288);
  size_t o_wqk  = alloc(4194304);
  size_t o_T    = alloc((size_t)NB * QN * TLD * 4);
  size_t o_pb   = alloc(65536);
  size_t o_g    = alloc((size_t)NB * NMEM * GLD * 2);   // 10,240,000

  float* summ  = (float*)(ws + o_sum);
  float* den   = (float*)(ws + o_den);
  float* pos   = (float*)(ws + o_pos);
  float* bfold = (float*)(ws + o_bf);
  int*   ti    = (int*)  (ws + o_ti);
  float* wt    = (float*)(ws + o_wt);
  int*   flagp = (int*)  (ws + o_flag);
  float* W2buf = (float*)(ws + o_w2);
  float* u_ext = (float*)(ws + o_uex);
  float* summText = (float*)(ws + o_st);
  float* betag = (float*)(ws + o_bg);
  float* v2    = (float*)(ws + o_v2);
  float* gbuf  = (float*)(ws + o_gm);
  float* logit = (float*)(ws + o_lg);
  float* osc5  = (float*)(ws + o_osc5);
  float* skwT  = (float*)(ws + o_skt);
  unsigned short* qb   = (unsigned short*)(ws + o_qbf);
  unsigned short* wqk  = (unsigned short*)(ws + o_wqk);
  float* Tbuf  = (float*)(ws + o_T);
  unsigned short* PB   = (unsigned short*)(ws + o_pb);
  unsigned short* gall = (unsigned short*)(ws + o_g);

  bigsetup_kernel<<<dim3(710), dim3(256), 0, stream>>>(
      sk_w, mask, out_w, out_b, fc2_w, fc2_b, sq_w, sq_b, sk_b, q_w, kv_w, queries,
      skwT, pos, flagp, bfold, W2buf, v2, gbuf, wqk, qb, PB);

  main_kernel<<<dim3(2884), dim3(512), 0, stream>>>(
      memories, pos, mask, flagp, PB, summ, den, gall, qb, wqk, Tbuf, sq_w, skwT, W2buf);

  ustb_kernel<<<dim3(1525), dim3(256), 0, stream>>>(
      queries, W2buf, u_ext, summ, v2, gbuf, summText, betag);
  logits_nn<<<dim3(16, 10, NB), dim3(256), 0, stream>>>(u_ext, summText, betag, den, logit);
  topk_kernel<<<dim3(NB * QN), dim3(256), 0, stream>>>(logit, ti, wt);

  attn5_kernel<<<dim3(NB * QN * TOPKK), dim3(256), 0, stream>>>(
      Tbuf, memories, pos, gall, ti, wt, mask, flagp, osc5);
  final5_kernel<<<dim3(NB * QN), dim3(64), 0, stream>>>(osc5, bfold, out);
}

// Round 13
// 308.417 us; speedup vs baseline: 1.0071x; 1.0071x over previous
//
#include <hip/hip_runtime.h>
#include <hip/hip_bf16.h>
#include <float.h>
#include <math.h>

// Problem constants
#define NB      4
#define QN      128
#define HID     512
#define NMEM    20000
#define NCHUNK  625
#define CHUNK   32
#define HEADS   8
#define DHEAD   64
#define TOPKK   8
#define NKV     1024
#define GLD     64       // G buffer ld (40 used cols)
#define LOGIT_SCALE 0.044194173824159216f  // 512^-0.5
#define W2LD    576
#define STROWS  520
#define LGLD    640
#define TLD     4096     // T ld: 8 heads x 512

typedef __attribute__((ext_vector_type(8))) short bf16x8;
typedef __attribute__((ext_vector_type(4))) short bf16x4;
typedef __attribute__((ext_vector_type(4))) float f32x4;

__device__ __forceinline__ short f2bf(float f){
  __hip_bfloat16 h = __float2bfloat16(f);
  return *reinterpret_cast<short*>(&h);
}
__device__ __forceinline__ float bf2f(unsigned short s){
  __hip_bfloat16 h;
  *reinterpret_cast<unsigned short*>(&h) = s;
  return __bfloat162float(h);
}
__device__ __forceinline__ bool mask_at(const void* m, int flag, long i){
  return flag ? (((const unsigned char*)m)[i] != 0)
              : (((const int*)m)[i] != 0);
}
__device__ __forceinline__ void gload16(const void* g, void* l){
  __builtin_amdgcn_global_load_lds((const __attribute__((address_space(1))) void*)g,
                                   (__attribute__((address_space(3))) void*)l, 16, 0, 0);
}

// ---------------- bigsetup: skwt + pos/flag + bfold + vker + wqk + qbf + PB(inline Wf) ----------------
// grid 710: [0,64) skwt; [64,128) pos/flag; [128] bfold; [129,134) vker;
//           [134,390) wqk; [390,646) qbf; [646,710) PB
__global__ __launch_bounds__(256) void bigsetup_kernel(const float* __restrict__ skw,
                                                       const void* __restrict__ mask,
                                                       const float* __restrict__ out_w,
                                                       const float* __restrict__ out_b,
                                                       const float* __restrict__ fc2_w,
                                                       const float* __restrict__ fc2_b,
                                                       const float* __restrict__ sq_w,
                                                       const float* __restrict__ sq_b,
                                                       const float* __restrict__ sk_b,
                                                       const float* __restrict__ q_w,
                                                       const float* __restrict__ kvw,
                                                       const float* __restrict__ queries,
                                                       float* __restrict__ skwT,
                                                       float* __restrict__ pos,
                                                       int* __restrict__ flagp,
                                                       float* __restrict__ bfold,
                                                       float* __restrict__ W2buf,
                                                       float* __restrict__ v2,
                                                       float* __restrict__ gbuf,
                                                       unsigned short* __restrict__ wqk,
                                                       unsigned short* __restrict__ qb,
                                                       unsigned short* __restrict__ PB){
  __shared__ float sm[12480];   // 49,920 B pool
  int sub = blockIdx.x;
  int t = threadIdx.x;
  if (sub < 64){
    float (*tile)[65] = (float(*)[65])sm;
    int c = t & 63, rbase = t >> 6;
    int e0 = (sub >> 3) * 64, j0 = (sub & 7) * 64;
#pragma unroll
    for (int j = 0; j < 16; ++j){
      int r = rbase + j * 4;
      tile[r][c] = skw[(long)(e0 + r) * 512 + j0 + c];
    }
    __syncthreads();
#pragma unroll
    for (int j = 0; j < 16; ++j){
      int rj = rbase + j * 4;
      skwT[(long)(j0 + rj) * 512 + e0 + c] = tile[c][rj];
    }
  } else if (sub < 128){
    int s = sub - 64;              // 0..63
    int cc = s >> 1;               // 0..31
    int d = (s & 1) * 256 + t;     // 0..511
    int j = (d < 256) ? d : d - 256;
    float invf = expf(-((2.0f * (float)j) / 512.0f) * 9.2103403719761836f);
    float arg = (float)(31 - cc) * invf;
    pos[cc * 512 + d] = (d < 256) ? sinf(arg) : cosf(arg);
    if (s == 0 && t == 0){
      const unsigned char* mb = (const unsigned char*)mask;
      *flagp = (mb[1] != 0) ? 1 : 0;
    }
  } else if (sub == 128){
    if (t < 5){
      float sb = 0.f;
      for (int k = 0; k < 512; ++k) sb += out_b[k] * fc2_w[k * 5 + t];
      bfold[t] = sb + fc2_b[t];
    }
  } else if (sub < 134){
    int s = sub - 129;             // 0..4
    if (s < 2){
      int d = s * 256 + t;
      float acc = 0.f;
      for (int j = 0; j < 512; ++j) acc += sq_w[(long)d * 512 + j] * sk_b[j];
      W2buf[(long)d * W2LD + 512] = acc;
      for (int cc = 513; cc < W2LD; ++cc) W2buf[(long)d * W2LD + cc] = 0.f;
    } else if (s < 4){
      int e = (s - 2) * 256 + t;
      float acc = 0.f;
      for (int j = 0; j < 512; ++j) acc += skw[(long)e * 512 + j] * sq_b[j];
      v2[e] = acc;
    } else {
      __shared__ float g[256];
      g[t] = sq_b[t] * sk_b[t] + sq_b[t + 256] * sk_b[t + 256];
      __syncthreads();
      for (int d = 128; d >= 1; d >>= 1){
        if (t < d) g[t] += g[t + d];
        __syncthreads();
      }
      if (t == 0) gbuf[0] = g[0];
    }
  } else if (sub < 390){
    // wqk: W_qk[h*512+d'][d] = 0.125 * sum_e kv_w[d'][h*64+e]*q_w[d][h*64+e]
    int bx = sub - 134;
    int h = bx >> 5, rem2 = bx & 31, dp = rem2 >> 2, dd = rem2 & 3;
    int dpr0 = dp * 64, dd0 = dd * 128;
    float (*Akv)[65] = (float(*)[65])sm;
    float (*Bq)[65]  = (float(*)[65])(sm + 64 * 65);
    for (int idx = t; idx < 64 * 64; idx += 256){
      int r = idx >> 6, e = idx & 63;
      Akv[r][e] = kvw[(long)(dpr0 + r) * NKV + h * 64 + e];
    }
    for (int idx = t; idx < 128 * 64; idx += 256){
      int r = idx >> 6, e = idx & 63;
      Bq[r][e] = q_w[(long)(dd0 + r) * 512 + h * 64 + e];
    }
    __syncthreads();
    int ty = t >> 4, tx = t & 15;
    float acc[4][8] = {};
    for (int e = 0; e < 64; ++e){
      float a0 = Akv[ty * 4 + 0][e], a1 = Akv[ty * 4 + 1][e];
      float a2 = Akv[ty * 4 + 2][e], a3 = Akv[ty * 4 + 3][e];
      float b[8];
#pragma unroll
      for (int v = 0; v < 8; ++v) b[v] = Bq[tx * 8 + v][e];
#pragma unroll
      for (int v = 0; v < 8; ++v){
        acc[0][v] += a0 * b[v];
        acc[1][v] += a1 * b[v];
        acc[2][v] += a2 * b[v];
        acc[3][v] += a3 * b[v];
      }
    }
#pragma unroll
    for (int u = 0; u < 4; ++u)
#pragma unroll
      for (int v = 0; v < 8; ++v)
        wqk[(long)(h * 512 + dpr0 + ty * 4 + u) * 512 + dd0 + tx * 8 + v] =
            (unsigned short)f2bf(acc[u][v] * 0.125f);
  } else if (sub < 646){
    long idx = (long)(sub - 390) * 256 + t;
    float4 v = *(const float4*)(queries + idx * 4);
    ushort4 o;
    o.x = (unsigned short)f2bf(v.x);
    o.y = (unsigned short)f2bf(v.y);
    o.z = (unsigned short)f2bf(v.z);
    o.w = (unsigned short)f2bf(v.w);
    *(ushort4*)(qb + idx * 4) = o;
  } else {
    // PB rows: row<40 => P[d][hj] via inline Wf column; else zero
    int row = sub - 646;           // 0..63
    if (row < 40){
      int h = row / 5, j = row - h * 5;
      __shared__ float wfc[64];
      if (t < 64){
        const float* owr = out_w + (long)(h * 64 + t) * 512;
        float s = 0.f;
        for (int k = 0; k < 512; ++k) s += owr[k] * fc2_w[k * 5 + j];
        wfc[t] = s;
      }
      __syncthreads();
      for (int d = t; d < 512; d += 256){
        const float* kr = kvw + (long)d * NKV + 512 + h * 64;
        float s = 0.f;
#pragma unroll
        for (int e = 0; e < 64; ++e) s += kr[e] * wfc[e];
        PB[(long)row * 512 + d] = (unsigned short)f2bf(s);
      }
    } else {
      for (int d = t; d < 512; d += 256) PB[(long)row * 512 + d] = 0;
    }
  }
}

// ---------------- main: [0,2500) prepsum+G ; [2500,2628) tgemm ; [2628,2884) W2 gemm ----------------
// LDS pool = 40,960 B exactly -> 4 blocks/CU.
__global__ __launch_bounds__(512) void main_kernel(const float* __restrict__ memories,
                                                   const float* __restrict__ pos,
                                                   const void* __restrict__ mask,
                                                   const int* __restrict__ flagp,
                                                   const unsigned short* __restrict__ PB,
                                                   float* __restrict__ summ,
                                                   float* __restrict__ chunkden,
                                                   unsigned short* __restrict__ g_all,
                                                   const unsigned short* __restrict__ Aq,
                                                   const unsigned short* __restrict__ Bw,
                                                   float* __restrict__ T,
                                                   const float* __restrict__ sq_w,
                                                   const float* __restrict__ skwT,
                                                   float* __restrict__ W2buf){
  __shared__ char pool[40960];
  int blk = blockIdx.x;
  int t = threadIdx.x;
  int lane = t & 63, wid = t >> 6;
  int lr = lane & 15, lg = lane >> 4;

  if (blk < 2500){
    // ===== prepsum + fused G-GEMM, one chunk per block =====
    // A_lds[32][512] bf16 XOR-swizzled (group ^= row&7), red[256][8] two-step reduce.
    int b = blk / NCHUNK, n = blk - b * NCHUNK;
    unsigned short* A_lds = (unsigned short*)pool;              // 32,768 B
    float (*red)[8] = (float(*)[8])(pool + 32768);              // 8,192 B
    long mbase = (long)b * NMEM + (long)n * CHUNK;
    int flag = *flagp;
    bool mybit = mask_at(mask, flag, mbase + (t & 31));
    unsigned int m32 = (unsigned int)__ballot(mybit);
    float den = (float)__popc(m32);
    int rh = t >> 6;               // 0..7 (== wid)
    int c8 = t & 63;               // 8-elem col group
    int swzg = (c8 ^ rh) * 8;      // swizzled elem offset (row&7 == rh for rows rh+8j)
    const float* base = memories + mbase * HID + c8 * 8;
    const float* pbase = pos + c8 * 8;
    float acc8[8] = {};
#pragma unroll
    for (int j = 0; j < 4; ++j){
      int row = rh + 8 * j;
      float4 va = *(const float4*)(base + (long)row * HID);
      float4 vb = *(const float4*)(base + (long)row * HID + 4);
      float4 pa = *(const float4*)(pbase + row * HID);
      float4 pb4 = *(const float4*)(pbase + row * HID + 4);
      ushort4 lo, hi;
      lo.x = (unsigned short)f2bf(va.x + pa.x);
      lo.y = (unsigned short)f2bf(va.y + pa.y);
      lo.z = (unsigned short)f2bf(va.z + pa.z);
      lo.w = (unsigned short)f2bf(va.w + pa.w);
      hi.x = (unsigned short)f2bf(vb.x + pb4.x);
      hi.y = (unsigned short)f2bf(vb.y + pb4.y);
      hi.z = (unsigned short)f2bf(vb.z + pb4.z);
      hi.w = (unsigned short)f2bf(vb.w + pb4.w);
      unsigned short* dst = A_lds + (long)row * 512 + swzg;
      *(ushort4*)dst = lo;
      *(ushort4*)(dst + 4) = hi;
      if (m32 & (1u << row)){
        acc8[0] += va.x; acc8[1] += va.y; acc8[2] += va.z; acc8[3] += va.w;
        acc8[4] += vb.x; acc8[5] += vb.y; acc8[6] += vb.z; acc8[7] += vb.w;
      }
    }
    if (t < 256){
#pragma unroll
      for (int k = 0; k < 8; ++k) red[t][k] = acc8[k];
    }
    __syncthreads();
    if (t >= 256){
#pragma unroll
      for (int k = 0; k < 8; ++k) red[t - 256][k] += acc8[k];
    }
    __syncthreads();
    if (rh == 0){
      float s[8];
#pragma unroll
      for (int k = 0; k < 8; ++k)
        s[k] = red[c8][k] + red[64 + c8][k] + red[128 + c8][k] + red[192 + c8][k];
      float dv = den + 1e-5f;
      float4 s0 = {s[0] / dv, s[1] / dv, s[2] / dv, s[3] / dv};
      float4 s1 = {s[4] / dv, s[5] / dv, s[6] / dv, s[7] / dv};
      float* srow = summ + ((long)b * NCHUNK + n) * 512 + c8 * 8;
      *(float4*)srow = s0;
      *(float4*)(srow + 4) = s1;
      if (t == 0) chunkden[b * NCHUNK + n] = den;
    }
    // fused G: 6 waves, each one 16x16 tile of A[32x512] @ PB^T[512x48]; full unroll -> loads pipelined
    if (wid < 6){
      int mt = wid / 3, nt = wid - mt * 3;
      int row = mt * 16 + lr;
      int r7 = row & 7;
      f32x4 acc4 = (f32x4)0.f;
#pragma unroll
      for (int k0 = 0; k0 < 512; k0 += 32){
        int g0 = (k0 >> 3) + lg;
        bf16x8 af = *(const bf16x8*)(A_lds + (long)row * 512 + ((g0 ^ r7) << 3));
        bf16x8 bv = *(const bf16x8*)(PB + (long)(nt * 16 + lr) * 512 + k0 + lg * 8);
        acc4 = __builtin_amdgcn_mfma_f32_16x16x32_bf16(af, bv, acc4, 0, 0, 0);
      }
      int col = nt * 16 + lr;
      if (col < 40){
        unsigned short* gout = g_all + (size_t)b * NMEM * GLD;
#pragma unroll
        for (int rr = 0; rr < 4; ++rr){
          int orow = n * CHUNK + mt * 16 + lg * 4 + rr;
          gout[(long)orow * GLD + col] = (unsigned short)f2bf(acc4[rr]);
        }
      }
    }
  } else if (blk < 2628){
    // ===== tgemm: T = qbf @ wqk^T (f32 out), 128x128 tile, 8 waves =====
    int L2 = blk - 2500;
    int panel = L2 >> 5, nb = L2 & 31;
    int m0 = panel << 7, n0 = nb << 7;
    unsigned short* As[2] = { (unsigned short*)pool, (unsigned short*)(pool + 8192) };
    unsigned short* Bs[2] = { (unsigned short*)(pool + 16384), (unsigned short*)(pool + 24576) };
    int srow = t >> 2, scol = (t & 3) * 8;
    int wr = wid >> 2, wc = wid & 3;
    const unsigned short* gA = Aq + (long)(m0 + srow) * 512 + scol;
    const unsigned short* gB = Bw + (long)(n0 + srow) * 512 + scol;
    int lofs = srow * 32 + scol;

    f32x4 acc[4][2];
#pragma unroll
    for (int i = 0; i < 4; ++i){ acc[i][0] = (f32x4)0.f; acc[i][1] = (f32x4)0.f; }

#define TSTAGE(B, K0) { gload16(gA + (K0), &As[B][lofs]); gload16(gB + (K0), &Bs[B][lofs]); }
#define TCOMPUTE(B) { bf16x8 af[4], bfv[2]; \
  _Pragma("unroll") for (int mi = 0; mi < 4; ++mi) af[mi]  = *(const bf16x8*)&As[B][(wr * 64 + mi * 16 + lr) * 32 + lg * 8]; \
  _Pragma("unroll") for (int ni = 0; ni < 2; ++ni) bfv[ni] = *(const bf16x8*)&Bs[B][(wc * 32 + ni * 16 + lr) * 32 + lg * 8]; \
  _Pragma("unroll") for (int mi = 0; mi < 4; ++mi) \
    _Pragma("unroll") for (int ni = 0; ni < 2; ++ni) \
      acc[mi][ni] = __builtin_amdgcn_mfma_f32_16x16x32_bf16(af[mi], bfv[ni], acc[mi][ni], 0, 0, 0); }

    TSTAGE(0, 0);
    __syncthreads();
#pragma unroll 1
    for (int tt = 0; tt < 16; tt += 2){
      if (tt + 1 < 16) TSTAGE(1, (tt + 1) * 32);
      TCOMPUTE(0);
      __syncthreads();
      if (tt + 2 < 16) TSTAGE(0, (tt + 2) * 32);
      TCOMPUTE(1);
      __syncthreads();
    }
#undef TSTAGE
#undef TCOMPUTE

#pragma unroll
    for (int mi = 0; mi < 4; ++mi)
#pragma unroll
      for (int ni = 0; ni < 2; ++ni)
#pragma unroll
        for (int rr = 0; rr < 4; ++rr){
          int gr = m0 + wr * 64 + mi * 16 + lg * 4 + rr;
          int gn = n0 + wc * 32 + ni * 16 + lr;
          T[(long)gr * TLD + gn] = acc[mi][ni][rr];
        }
  } else {
    // ===== W2 = sq_w @ skwT (f32), 2 rows/wave, 8 waves => 16 rows/block =====
    int bx2 = blk - 2628;           // 0..255
    int rt = bx2 & 31, nt2 = bx2 >> 5;
    int r0 = rt * 16 + wid * 2;
    int nn = nt2 * 64 + lane;
    const float* a0 = sq_w + (long)r0 * 512;
    const float* bp = skwT + nn;
    float acc0 = 0.f, acc1 = 0.f;
#pragma unroll 4
    for (int k = 0; k < 512; k += 4){
      float b0 = bp[(long)k * 512];
      float b1 = bp[(long)(k + 1) * 512];
      float b2 = bp[(long)(k + 2) * 512];
      float b3 = bp[(long)(k + 3) * 512];
      float4 a;
      a = *(const float4*)(a0 + k);
      acc0 += a.x * b0 + a.y * b1 + a.z * b2 + a.w * b3;
      a = *(const float4*)(a0 + 512 + k);
      acc1 += a.x * b0 + a.y * b1 + a.z * b2 + a.w * b3;
    }
    W2buf[(long)r0 * W2LD + nn]       = acc0;
    W2buf[(long)(r0 + 1) * W2LD + nn] = acc1;
  }
}

// ---------------- ustb: blocks [0,576) u_ext (2 rows/wave); [576,1525) stbeta ----------------
__global__ __launch_bounds__(256) void ustb_kernel(const float* __restrict__ queries,
                                                   const float* __restrict__ W2buf,
                                                   float* __restrict__ u_ext,
                                                   const float* __restrict__ summ,
                                                   const float* __restrict__ v2,
                                                   const float* __restrict__ gbuf,
                                                   float* __restrict__ summText,
                                                   float* __restrict__ betag){
  int blk = blockIdx.x;
  int t = threadIdx.x;
  if (blk < 576){
    int ax = blk & 63, ay = blk >> 6;
    int lane = t & 63, w = t >> 6;
    int r0 = ax * 8 + w * 2;
    int n  = ay * 64 + lane;
    const float* a0 = queries + (long)r0 * 512;
    const float* bp = W2buf + n;
    float acc0 = 0.f, acc1 = 0.f;
#pragma unroll 4
    for (int k = 0; k < 512; k += 4){
      float b0 = bp[(long)k * W2LD];
      float b1 = bp[(long)(k + 1) * W2LD];
      float b2 = bp[(long)(k + 2) * W2LD];
      float b3 = bp[(long)(k + 3) * W2LD];
      float4 a;
      a = *(const float4*)(a0 + k);
      acc0 += a.x * b0 + a.y * b1 + a.z * b2 + a.w * b3;
      a = *(const float4*)(a0 + 512 + k);
      acc1 += a.x * b0 + a.y * b1 + a.z * b2 + a.w * b3;
    }
    u_ext[(long)r0 * W2LD + n]       = acc0;
    u_ext[(long)(r0 + 1) * W2LD + n] = acc1;
  } else if (blk < 896){
    __shared__ float tile[64][65];
    int b2 = blk - 576;
    int b = b2 / 80; int rem = b2 % 80;
    int n0 = (rem / 8) * 64, e0 = (rem % 8) * 64;
    int c = t & 63, rbase = t >> 6;
#pragma unroll
    for (int j = 0; j < 16; ++j){
      int r = rbase + j * 4;
      int n = n0 + r;
      tile[r][c] = (n < NCHUNK) ? summ[((long)b * NCHUNK + n) * 512 + e0 + c] : 0.f;
    }
    __syncthreads();
#pragma unroll
    for (int j = 0; j < 16; ++j){
      int re = rbase + j * 4;
      summText[(long)b * STROWS * LGLD + (long)(e0 + re) * LGLD + n0 + c] = tile[c][re];
    }
  } else if (blk < 900){
    int b = blk - 896;
    for (int idx = t; idx < 8 * LGLD; idx += 256){
      int e = idx / LGLD, n = idx - e * LGLD;
      summText[(long)b * STROWS * LGLD + (long)(512 + e) * LGLD + n] = (e == 0) ? 1.f : 0.f;
    }
  } else {
    int bb = blk - 900;
    int w = t >> 6, lane = t & 63;
    int row = bb * 4 + w;
    const float* r = summ + (long)row * 512;
    float s = 0.f;
#pragma unroll
    for (int c = 0; c < 8; ++c) s += r[lane + 64 * c] * v2[lane + 64 * c];
    for (int d = 32; d >= 1; d >>= 1) s += __shfl_xor(s, d, 64);
    if (lane == 0){
      int b = row / NCHUNK, n = row % NCHUNK;
      betag[b * LGLD + n] = s + gbuf[0];
    }
  }
}

// ---------------- logits (NN form): 2 rows/wave, grid (16,10,NB) ----------------
__global__ __launch_bounds__(256) void logits_nn(const float* __restrict__ u_ext,
                                                 const float* __restrict__ summText,
                                                 const float* __restrict__ betag,
                                                 const float* __restrict__ chunkden,
                                                 float* __restrict__ logits){
  int b = blockIdx.z;
  int tid = threadIdx.x;
  int lane = tid & 63, w = tid >> 6;
  int r0 = blockIdx.x * 8 + w * 2;
  int n  = blockIdx.y * 64 + lane;
  const float* a0 = u_ext + ((long)b * QN + r0) * W2LD;
  const float* bp = summText + (long)b * STROWS * LGLD + n;
  float acc0 = 0.f, acc1 = 0.f;
#pragma unroll 4
  for (int k = 0; k < STROWS; k += 4){
    float b0 = bp[(long)k * LGLD];
    float b1 = bp[(long)(k + 1) * LGLD];
    float b2 = bp[(long)(k + 2) * LGLD];
    float b3 = bp[(long)(k + 3) * LGLD];
    float4 a;
    a = *(const float4*)(a0 + k);
    acc0 += a.x * b0 + a.y * b1 + a.z * b2 + a.w * b3;
    a = *(const float4*)(a0 + W2LD + k);
    acc1 += a.x * b0 + a.y * b1 + a.z * b2 + a.w * b3;
  }
  if (n < NCHUNK){
    float bet = betag[b * LGLD + n];
    bool dead = (chunkden[b * NCHUNK + n] <= 0.f);
    float v0 = (acc0 + bet) * LOGIT_SCALE;
    float v1 = (acc1 + bet) * LOGIT_SCALE;
    if (dead){ v0 = v1 = -FLT_MAX; }
    long base = ((long)b * QN + r0) * LGLD + n;
    logits[base]        = v0;
    logits[base + LGLD] = v1;
  }
}

// ---------------- top-8 + softmax weights, 4 waves per (b,i) row ----------------
__global__ __launch_bounds__(256) void topk_kernel(const float* __restrict__ logits,
                                                   int* __restrict__ topi_out,
                                                   float* __restrict__ wts_out){
  int row = blockIdx.x;
  __shared__ float lds[NCHUNK];
  __shared__ float wv[4];
  __shared__ int   wi[4];
  __shared__ float topv[TOPKK];
  __shared__ int   topi[TOPKK];
  int t = threadIdx.x;
  int lane = t & 63, w = t >> 6;
  for (int idx = t; idx < NCHUNK; idx += 256) lds[idx] = logits[(long)row * LGLD + idx];
  __syncthreads();
  for (int it = 0; it < TOPKK; ++it){
    float bv = -INFINITY; int bi = 0x7fffffff;
    for (int idx = t; idx < NCHUNK; idx += 256){
      float v = lds[idx];
      if (v > bv){ bv = v; bi = idx; }
    }
    for (int d = 32; d >= 1; d >>= 1){
      float ov = __shfl_xor(bv, d, 64);
      int   oi = __shfl_xor(bi, d, 64);
      if (ov > bv || (ov == bv && oi < bi)){ bv = ov; bi = oi; }
    }
    if (lane == 0){ wv[w] = bv; wi[w] = bi; }
    __syncthreads();
    if (t == 0){
      float fb = wv[0]; int fi = wi[0];
      for (int j = 1; j < 4; ++j){
        if (wv[j] > fb || (wv[j] == fb && wi[j] < fi)){ fb = wv[j]; fi = wi[j]; }
      }
      topv[it] = fb; topi[it] = fi; lds[fi] = -INFINITY;
    }
    __syncthreads();
  }
  if (t == 0){
    float m = topv[0];
    for (int r = 1; r < TOPKK; ++r) m = fmaxf(m, topv[r]);
    float e[TOPKK], s = 0.f;
    for (int r = 0; r < TOPKK; ++r){ e[r] = expf(topv[r] - m); s += e[r]; }
    for (int r = 0; r < TOPKK; ++r){
      wts_out[(long)row * TOPKK + r] = e[r] / s;
      topi_out[(long)row * TOPKK + r] = topi[r];
    }
  }
}

// ---------------- attention: A staged from memories+pos (L3-hot), sim = T.A, G-fold out ----------------
#define ALDP 516   // attn A_lds row stride (bf16): 8B-aligned, 2-way-free for sim reads
__global__ __launch_bounds__(256) void attn5_kernel(const float* __restrict__ T,
                                                    const float* __restrict__ memories,
                                                    const float* __restrict__ pos,
                                                    const unsigned short* __restrict__ g_all,
                                                    const int* __restrict__ topidx,
                                                    const float* __restrict__ wts,
                                                    const void* __restrict__ mask,
                                                    const int* __restrict__ flagp,
                                                    float* __restrict__ osc5){
  int bx = blockIdx.x;
  int bb = bx >> 10, rem = bx & 1023;
  int i = rem >> 3, k = rem & 7;
  const unsigned short* gb = g_all + (size_t)bb * NMEM * GLD;
  int t = threadIdx.x;
  __shared__ unsigned short A_lds[32 * ALDP];
  __shared__ float T_lds[TLD];
  __shared__ float red[4][5];
  int flag = *flagp;
  long sel = ((long)(bb * QN + i)) * TOPKK + k;
  int chunk = topidx[sel];
  float w8 = wts[sel];
  const float* Trow = T + (long)(bb * QN + i) * TLD;
  for (int idx = t; idx < 1024; idx += 256)
    *(float4*)&T_lds[idx * 4] = *(const float4*)&Trow[idx * 4];
  {
    int r = t >> 3, cb = (t & 7) * 64;
    const float* src = memories + ((long)bb * NMEM + (long)chunk * CHUNK + r) * HID + cb;
    const float* ps  = pos + r * HID + cb;
    unsigned short* dst = &A_lds[r * ALDP + cb];
#pragma unroll
    for (int j = 0; j < 8; ++j){
      float4 m0 = *(const float4*)(src + j * 8);
      float4 m1 = *(const float4*)(src + j * 8 + 4);
      float4 p0 = *(const float4*)(ps + j * 8);
      float4 p1 = *(const float4*)(ps + j * 8 + 4);
      ushort4 lo, hi;
      lo.x = (unsigned short)f2bf(m0.x + p0.x);
      lo.y = (unsigned short)f2bf(m0.y + p0.y);
      lo.z = (unsigned short)f2bf(m0.z + p0.z);
      lo.w = (unsigned short)f2bf(m0.w + p0.w);
      hi.x = (unsigned short)f2bf(m1.x + p1.x);
      hi.y = (unsigned short)f2bf(m1.y + p1.y);
      hi.z = (unsigned short)f2bf(m1.z + p1.z);
      hi.w = (unsigned short)f2bf(m1.w + p1.w);
      *(ushort4*)(dst + j * 8)     = lo;
      *(ushort4*)(dst + j * 8 + 4) = hi;
    }
  }
  __syncthreads();
  int h = t >> 5, c = t & 31;
  const unsigned short* arow = &A_lds[c * ALDP];
  const float* tp = &T_lds[h * 512];
  float s = 0.f;
#pragma unroll 4
  for (int e8 = 0; e8 < 64; ++e8){
    bf16x4 alo = *(const bf16x4*)(arow + e8 * 8);
    bf16x4 ahi = *(const bf16x4*)(arow + e8 * 8 + 4);
    float4 ta = *(const float4*)(tp + e8 * 8);
    float4 tb = *(const float4*)(tp + e8 * 8 + 4);
    s += bf2f((unsigned short)alo[0]) * ta.x + bf2f((unsigned short)alo[1]) * ta.y
       + bf2f((unsigned short)alo[2]) * ta.z + bf2f((unsigned short)alo[3]) * ta.w
       + bf2f((unsigned short)ahi[0]) * tb.x + bf2f((unsigned short)ahi[1]) * tb.y
       + bf2f((unsigned short)ahi[2]) * tb.z + bf2f((unsigned short)ahi[3]) * tb.w;
  }
  bool mv = mask_at(mask, flag, (long)bb * NMEM + (long)chunk * CHUNK + c);
  if (!mv) s = -FLT_MAX;
  float m = s;
  for (int d = 16; d >= 1; d >>= 1) m = fmaxf(m, __shfl_xor(m, d, 32));
  float p = expf(s - m);
  float su = p;
  for (int d = 16; d >= 1; d >>= 1) su += __shfl_xor(su, d, 32);
  float att = p / su;
  const unsigned short* grow = gb + (long)(chunk * CHUNK + c) * GLD + h * 5;
  float p0 = att * bf2f(grow[0]);
  float p1 = att * bf2f(grow[1]);
  float p2 = att * bf2f(grow[2]);
  float p3 = att * bf2f(grow[3]);
  float p4 = att * bf2f(grow[4]);
#pragma unroll
  for (int d = 32; d >= 1; d >>= 1){
    p0 += __shfl_xor(p0, d, 64);
    p1 += __shfl_xor(p1, d, 64);
    p2 += __shfl_xor(p2, d, 64);
    p3 += __shfl_xor(p3, d, 64);
    p4 += __shfl_xor(p4, d, 64);
  }
  int w = t >> 6, lane = t & 63;
  if (lane == 0){
    red[w][0] = p0; red[w][1] = p1; red[w][2] = p2; red[w][3] = p3; red[w][4] = p4;
  }
  __syncthreads();
  if (t < 5){
    float tot = red[0][t] + red[1][t] + red[2][t] + red[3][t];
    osc5[sel * 8 + t] = w8 * tot;
  }
}

// ---------------- final5 ----------------
__global__ __launch_bounds__(64) void final5_kernel(const float* __restrict__ osc5,
                                                    const float* __restrict__ bfold,
                                                    float* __restrict__ out){
  int bi = blockIdx.x;
  int t = threadIdx.x;
  if (t < 5){
    float a = bfold[t];
#pragma unroll
    for (int k = 0; k < TOPKK; ++k) a += osc5[((long)bi * TOPKK + k) * 8 + t];
    out[bi * 5 + t] = a;
  }
}

extern "C" void kernel_launch(void* const* d_in, const int* in_sizes, int n_in,
                              void* d_out, int out_size, void* d_ws, size_t ws_size,
                              hipStream_t stream) {
  const float* queries  = (const float*)d_in[1];
  const float* memories = (const float*)d_in[2];
  const void*  mask     = d_in[3];
  const float* sq_w = (const float*)d_in[10];
  const float* sq_b = (const float*)d_in[11];
  const float* sk_w = (const float*)d_in[12];
  const float* sk_b = (const float*)d_in[13];
  const float* q_w  = (const float*)d_in[14];
  const float* kv_w = (const float*)d_in[15];
  const float* out_w = (const float*)d_in[16];
  const float* out_b = (const float*)d_in[17];
  const float* fc2_w = (const float*)d_in[18];
  const float* fc2_b = (const float*)d_in[19];
  float* out = (float*)d_out;

  char* ws = (char*)d_ws;
  size_t off = 0;
  auto alloc = [&](size_t bytes){ size_t o = off; off += (bytes + 511) & ~(size_t)511; return o; };
  size_t o_sum  = alloc(5120000);
  size_t o_den  = alloc(10240);
  size_t o_pos  = alloc(65536);
  size_t o_bf   = alloc(512);
  size_t o_ti   = alloc(16384);
  size_t o_wt   = alloc(16384);
  size_t o_flag = alloc(512);
  size_t o_w2   = alloc(1179648);
  size_t o_uex  = alloc(1179648);
  size_t o_st   = alloc(5324800);
  size_t o_bg   = alloc(10240);
  size_t o_v2   = alloc(2048);
  size_t o_gm   = alloc(512);
  size_t o_lg   = alloc(1310720);
  size_t o_osc5 = alloc(131072);
  size_t o_skt  = alloc(1048576);
  size_t o_qbf  = alloc(524288);
  size_t o_wqk  = alloc(4194304);
  size_t o_T    = alloc((size_t)NB * QN * TLD * 4);
  size_t o_pb   = alloc(65536);
  size_t o_g    = alloc((size_t)NB * NMEM * GLD * 2);   // 10,240,000

  float* summ  = (float*)(ws + o_sum);
  float* den   = (float*)(ws + o_den);
  float* pos   = (float*)(ws + o_pos);
  float* bfold = (float*)(ws + o_bf);
  int*   ti    = (int*)  (ws + o_ti);
  float* wt    = (float*)(ws + o_wt);
  int*   flagp = (int*)  (ws + o_flag);
  float* W2buf = (float*)(ws + o_w2);
  float* u_ext = (float*)(ws + o_uex);
  float* summText = (float*)(ws + o_st);
  float* betag = (float*)(ws + o_bg);
  float* v2    = (float*)(ws + o_v2);
  float* gbuf  = (float*)(ws + o_gm);
  float* logit = (float*)(ws + o_lg);
  float* osc5  = (float*)(ws + o_osc5);
  float* skwT  = (float*)(ws + o_skt);
  unsigned short* qb   = (unsigned short*)(ws + o_qbf);
  unsigned short* wqk  = (unsigned short*)(ws + o_wqk);
  float* Tbuf  = (float*)(ws + o_T);
  unsigned short* PB   = (unsigned short*)(ws + o_pb);
  unsigned short* gall = (unsigned short*)(ws + o_g);

  bigsetup_kernel<<<dim3(710), dim3(256), 0, stream>>>(
      sk_w, mask, out_w, out_b, fc2_w, fc2_b, sq_w, sq_b, sk_b, q_w, kv_w, queries,
      skwT, pos, flagp, bfold, W2buf, v2, gbuf, wqk, qb, PB);

  main_kernel<<<dim3(2884), dim3(512), 0, stream>>>(
      memories, pos, mask, flagp, PB, summ, den, gall, qb, wqk, Tbuf, sq_w, skwT, W2buf);

  ustb_kernel<<<dim3(1525), dim3(256), 0, stream>>>(
      queries, W2buf, u_ext, summ, v2, gbuf, summText, betag);
  logits_nn<<<dim3(16, 10, NB), dim3(256), 0, stream>>>(u_ext, summText, betag, den, logit);
  topk_kernel<<<dim3(NB * QN), dim3(256), 0, stream>>>(logit, ti, wt);

  attn5_kernel<<<dim3(NB * QN * TOPKK), dim3(256), 0, stream>>>(
      Tbuf, memories, pos, gall, ti, wt, mask, flagp, osc5);
  final5_kernel<<<dim3(NB * QN), dim3(64), 0, stream>>>(osc5, bfold, out);
}

// Round 14
// 275.502 us; speedup vs baseline: 1.1274x; 1.1195x over previous
//
#include <hip/hip_runtime.h>
#include <hip/hip_bf16.h>
#include <float.h>
#include <math.h>

// Problem constants
#define NB      4
#define QN      128
#define HID     512
#define NMEM    20000
#define MPAD    20096    // 157*128
#define NCHUNK  625
#define CHUNK   32
#define HEADS   8
#define DHEAD   64
#define TOPKK   8
#define NKV     1024
#define GLD     64       // G buffer ld (40 used cols)
#define LOGIT_SCALE 0.044194173824159216f  // 512^-0.5
#define W2LD    576
#define STROWS  520
#define LGLD    640
#define TLD     4096     // T ld: 8 heads x 512

typedef __attribute__((ext_vector_type(8))) short bf16x8;
typedef __attribute__((ext_vector_type(4))) short bf16x4;
typedef __attribute__((ext_vector_type(4))) float f32x4;

__device__ __forceinline__ short f2bf(float f){
  __hip_bfloat16 h = __float2bfloat16(f);
  return *reinterpret_cast<short*>(&h);
}
__device__ __forceinline__ float bf2f(unsigned short s){
  __hip_bfloat16 h;
  *reinterpret_cast<unsigned short*>(&h) = s;
  return __bfloat162float(h);
}
__device__ __forceinline__ bool mask_at(const void* m, int flag, long i){
  return flag ? (((const unsigned char*)m)[i] != 0)
              : (((const int*)m)[i] != 0);
}
__device__ __forceinline__ void gload16(const void* g, void* l){
  __builtin_amdgcn_global_load_lds((const __attribute__((address_space(1))) void*)g,
                                   (__attribute__((address_space(3))) void*)l, 16, 0, 0);
}

// ---------------- bigsetup: skwt + pos/flag + bfold + vker + wqk + qbf + PB(inline Wf) ----------------
// grid 710: [0,64) skwt; [64,128) pos/flag; [128] bfold; [129,134) vker;
//           [134,390) wqk; [390,646) qbf; [646,710) PB
__global__ __launch_bounds__(256) void bigsetup_kernel(const float* __restrict__ skw,
                                                       const void* __restrict__ mask,
                                                       const float* __restrict__ out_w,
                                                       const float* __restrict__ out_b,
                                                       const float* __restrict__ fc2_w,
                                                       const float* __restrict__ fc2_b,
                                                       const float* __restrict__ sq_w,
                                                       const float* __restrict__ sq_b,
                                                       const float* __restrict__ sk_b,
                                                       const float* __restrict__ q_w,
                                                       const float* __restrict__ kvw,
                                                       const float* __restrict__ queries,
                                                       float* __restrict__ skwT,
                                                       float* __restrict__ pos,
                                                       int* __restrict__ flagp,
                                                       float* __restrict__ bfold,
                                                       float* __restrict__ W2buf,
                                                       float* __restrict__ v2,
                                                       float* __restrict__ gbuf,
                                                       unsigned short* __restrict__ wqk,
                                                       unsigned short* __restrict__ qb,
                                                       unsigned short* __restrict__ PB){
  __shared__ float sm[12480];
  int sub = blockIdx.x;
  int t = threadIdx.x;
  if (sub < 64){
    float (*tile)[65] = (float(*)[65])sm;
    int c = t & 63, rbase = t >> 6;
    int e0 = (sub >> 3) * 64, j0 = (sub & 7) * 64;
#pragma unroll
    for (int j = 0; j < 16; ++j){
      int r = rbase + j * 4;
      tile[r][c] = skw[(long)(e0 + r) * 512 + j0 + c];
    }
    __syncthreads();
#pragma unroll
    for (int j = 0; j < 16; ++j){
      int rj = rbase + j * 4;
      skwT[(long)(j0 + rj) * 512 + e0 + c] = tile[c][rj];
    }
  } else if (sub < 128){
    int s = sub - 64;
    int cc = s >> 1;
    int d = (s & 1) * 256 + t;
    int j = (d < 256) ? d : d - 256;
    float invf = expf(-((2.0f * (float)j) / 512.0f) * 9.2103403719761836f);
    float arg = (float)(31 - cc) * invf;
    pos[cc * 512 + d] = (d < 256) ? sinf(arg) : cosf(arg);
    if (s == 0 && t == 0){
      const unsigned char* mb = (const unsigned char*)mask;
      *flagp = (mb[1] != 0) ? 1 : 0;
    }
  } else if (sub == 128){
    if (t < 5){
      float sb = 0.f;
      for (int k = 0; k < 512; ++k) sb += out_b[k] * fc2_w[k * 5 + t];
      bfold[t] = sb + fc2_b[t];
    }
  } else if (sub < 134){
    int s = sub - 129;
    if (s < 2){
      int d = s * 256 + t;
      float acc = 0.f;
      for (int j = 0; j < 512; ++j) acc += sq_w[(long)d * 512 + j] * sk_b[j];
      W2buf[(long)d * W2LD + 512] = acc;
      for (int cc = 513; cc < W2LD; ++cc) W2buf[(long)d * W2LD + cc] = 0.f;
    } else if (s < 4){
      int e = (s - 2) * 256 + t;
      float acc = 0.f;
      for (int j = 0; j < 512; ++j) acc += skw[(long)e * 512 + j] * sq_b[j];
      v2[e] = acc;
    } else {
      __shared__ float g[256];
      g[t] = sq_b[t] * sk_b[t] + sq_b[t + 256] * sk_b[t + 256];
      __syncthreads();
      for (int d = 128; d >= 1; d >>= 1){
        if (t < d) g[t] += g[t + d];
        __syncthreads();
      }
      if (t == 0) gbuf[0] = g[0];
    }
  } else if (sub < 390){
    int bx = sub - 134;
    int h = bx >> 5, rem2 = bx & 31, dp = rem2 >> 2, dd = rem2 & 3;
    int dpr0 = dp * 64, dd0 = dd * 128;
    float (*Akv)[65] = (float(*)[65])sm;
    float (*Bq)[65]  = (float(*)[65])(sm + 64 * 65);
    for (int idx = t; idx < 64 * 64; idx += 256){
      int r = idx >> 6, e = idx & 63;
      Akv[r][e] = kvw[(long)(dpr0 + r) * NKV + h * 64 + e];
    }
    for (int idx = t; idx < 128 * 64; idx += 256){
      int r = idx >> 6, e = idx & 63;
      Bq[r][e] = q_w[(long)(dd0 + r) * 512 + h * 64 + e];
    }
    __syncthreads();
    int ty = t >> 4, tx = t & 15;
    float acc[4][8] = {};
    for (int e = 0; e < 64; ++e){
      float a0 = Akv[ty * 4 + 0][e], a1 = Akv[ty * 4 + 1][e];
      float a2 = Akv[ty * 4 + 2][e], a3 = Akv[ty * 4 + 3][e];
      float b[8];
#pragma unroll
      for (int v = 0; v < 8; ++v) b[v] = Bq[tx * 8 + v][e];
#pragma unroll
      for (int v = 0; v < 8; ++v){
        acc[0][v] += a0 * b[v];
        acc[1][v] += a1 * b[v];
        acc[2][v] += a2 * b[v];
        acc[3][v] += a3 * b[v];
      }
    }
#pragma unroll
    for (int u = 0; u < 4; ++u)
#pragma unroll
      for (int v = 0; v < 8; ++v)
        wqk[(long)(h * 512 + dpr0 + ty * 4 + u) * 512 + dd0 + tx * 8 + v] =
            (unsigned short)f2bf(acc[u][v] * 0.125f);
  } else if (sub < 646){
    long idx = (long)(sub - 390) * 256 + t;
    float4 v = *(const float4*)(queries + idx * 4);
    ushort4 o;
    o.x = (unsigned short)f2bf(v.x);
    o.y = (unsigned short)f2bf(v.y);
    o.z = (unsigned short)f2bf(v.z);
    o.w = (unsigned short)f2bf(v.w);
    *(ushort4*)(qb + idx * 4) = o;
  } else {
    int row = sub - 646;           // 0..63
    if (row < 40){
      int h = row / 5, j = row - h * 5;
      __shared__ float wfc[64];
      if (t < 64){
        const float* owr = out_w + (long)(h * 64 + t) * 512;
        float s = 0.f;
        for (int k = 0; k < 512; ++k) s += owr[k] * fc2_w[k * 5 + j];
        wfc[t] = s;
      }
      __syncthreads();
      for (int d = t; d < 512; d += 256){
        const float* kr = kvw + (long)d * NKV + 512 + h * 64;
        float s = 0.f;
#pragma unroll
        for (int e = 0; e < 64; ++e) s += kr[e] * wfc[e];
        PB[(long)row * 512 + d] = (unsigned short)f2bf(s);
      }
    } else {
      for (int d = t; d < 512; d += 256) PB[(long)row * 512 + d] = 0;
    }
  }
}

// ---------------- prepsum: memories -> summ + chunkden + bf16 abf (16B stores) ----------------
__global__ __launch_bounds__(512) void prepsum_kernel(const float* __restrict__ memories,
                                                      const float* __restrict__ pos,
                                                      const void* __restrict__ mask,
                                                      const int* __restrict__ flagp,
                                                      unsigned short* __restrict__ abf_all,
                                                      float* __restrict__ summ,
                                                      float* __restrict__ chunkden){
  int n = blockIdx.x, b = blockIdx.y;
  int t = threadIdx.x;
  unsigned short* abf = abf_all + (long)b * MPAD * 512;
  if (n == NCHUNK){
    for (int idx = t; idx < 96 * 128; idx += 512){
      ushort4 z = {0, 0, 0, 0};
      *(ushort4*)(abf + (long)(NMEM + (idx >> 7)) * 512 + (long)(idx & 127) * 4) = z;
    }
    return;
  }
  long mbase = (long)b * NMEM + (long)n * CHUNK;
  int flag = *flagp;
  bool mybit = mask_at(mask, flag, mbase + (t & 31));
  unsigned int m32 = (unsigned int)__ballot(mybit);
  float den = (float)__popc(m32);
  int rh = t >> 6;               // 0..7
  int c8 = t & 63;               // 8-elem col group
  const float* base = memories + mbase * HID + c8 * 8;
  const float* pbase = pos + c8 * 8;
  float4 va[4], vb[4], pa[4], pb[4];
#pragma unroll
  for (int j = 0; j < 4; ++j){
    va[j] = *(const float4*)(base + (long)(rh + 8 * j) * HID);
    vb[j] = *(const float4*)(base + (long)(rh + 8 * j) * HID + 4);
  }
#pragma unroll
  for (int j = 0; j < 4; ++j){
    pa[j] = *(const float4*)(pbase + (rh + 8 * j) * HID);
    pb[j] = *(const float4*)(pbase + (rh + 8 * j) * HID + 4);
  }
#pragma unroll
  for (int j = 0; j < 4; ++j){
    union { unsigned short u[8]; int4 v; } o;
    o.u[0] = (unsigned short)f2bf(va[j].x + pa[j].x);
    o.u[1] = (unsigned short)f2bf(va[j].y + pa[j].y);
    o.u[2] = (unsigned short)f2bf(va[j].z + pa[j].z);
    o.u[3] = (unsigned short)f2bf(va[j].w + pa[j].w);
    o.u[4] = (unsigned short)f2bf(vb[j].x + pb[j].x);
    o.u[5] = (unsigned short)f2bf(vb[j].y + pb[j].y);
    o.u[6] = (unsigned short)f2bf(vb[j].z + pb[j].z);
    o.u[7] = (unsigned short)f2bf(vb[j].w + pb[j].w);
    *(int4*)(abf + (long)(n * CHUNK + rh + 8 * j) * 512 + c8 * 8) = o.v;
  }
  float acc[8] = {};
#pragma unroll
  for (int j = 0; j < 4; ++j){
    if (m32 & (1u << (rh + 8 * j))){
      acc[0] += va[j].x; acc[1] += va[j].y; acc[2] += va[j].z; acc[3] += va[j].w;
      acc[4] += vb[j].x; acc[5] += vb[j].y; acc[6] += vb[j].z; acc[7] += vb[j].w;
    }
  }
  __shared__ float red[512][9];
#pragma unroll
  for (int k = 0; k < 8; ++k) red[t][k] = acc[k];
  __syncthreads();
  if (rh == 0){
    float s[8] = {};
    for (int g = 0; g < 8; ++g)
#pragma unroll
      for (int k = 0; k < 8; ++k) s[k] += red[g * 64 + c8][k];
    float dv = den + 1e-5f;
    float4 s0 = {s[0] / dv, s[1] / dv, s[2] / dv, s[3] / dv};
    float4 s1 = {s[4] / dv, s[5] / dv, s[6] / dv, s[7] / dv};
    float* srow = summ + ((long)b * NCHUNK + n) * 512 + c8 * 8;
    *(float4*)srow = s0;
    *(float4*)(srow + 4) = s1;
    if (t == 0) chunkden[b * NCHUNK + n] = den;
  }
}

// ---------------- gt_gemm: [0,316) ggemm; [316,444) tgemm; [444,956) W2 f32 gemm ----------------
__global__ __launch_bounds__(256) void gt_gemm(const unsigned short* __restrict__ abf_all,
                                               const unsigned short* __restrict__ PB,
                                               unsigned short* __restrict__ g_all,
                                               const unsigned short* __restrict__ Aq,
                                               const unsigned short* __restrict__ Bw,
                                               float* __restrict__ T,
                                               const float* __restrict__ sq_w,
                                               const float* __restrict__ skwT,
                                               float* __restrict__ W2buf){
  __shared__ unsigned short pool[20480];
  int blk = blockIdx.x;
  int tid = threadIdx.x, wid = tid >> 6, lane = tid & 63;
  int lr = lane & 15, lg = lane >> 4;
  int scol = (lane & 3) << 3;
  int srow = wid * 16 + (lane >> 2);

  if (blk < 316){
    // ===== ggemm: G = abf @ PB^T, 256 rows x 64 cols =====
    int bb = blk / 79, g = blk - bb * 79;
    const unsigned short* A = abf_all + (size_t)bb * MPAD * 512;
    unsigned short* gout = g_all + (size_t)bb * MPAD * GLD;
    unsigned short* As[2] = { pool, pool + 8192 };
    unsigned short* Bs[2] = { pool + 16384, pool + 18432 };
    long rbase = (long)g * 256 + srow;
    long ra0 = rbase;       if (ra0 > MPAD - 1) ra0 = MPAD - 1;
    long ra1 = rbase + 64;  if (ra1 > MPAD - 1) ra1 = MPAD - 1;
    long ra2 = rbase + 128; if (ra2 > MPAD - 1) ra2 = MPAD - 1;
    long ra3 = rbase + 192; if (ra3 > MPAD - 1) ra3 = MPAD - 1;
    const unsigned short* gA0 = A + ra0 * 512 + scol;
    const unsigned short* gA1 = A + ra1 * 512 + scol;
    const unsigned short* gA2 = A + ra2 * 512 + scol;
    const unsigned short* gA3 = A + ra3 * 512 + scol;
    const unsigned short* gB0 = PB + (long)srow * 512 + scol;
    int lA0 = (wid * 16) * 32, lA1 = (64 + wid * 16) * 32;
    int lA2 = (128 + wid * 16) * 32, lA3 = (192 + wid * 16) * 32;
    int lB0 = (wid * 16) * 32;

    f32x4 acc[4][4];
#pragma unroll
    for (int i = 0; i < 4; ++i)
#pragma unroll
      for (int j = 0; j < 4; ++j) acc[i][j] = (f32x4)0.f;

#define GSTAGE(B, K0) { gload16(gA0 + (K0), &As[B][lA0]); gload16(gA1 + (K0), &As[B][lA1]); \
                        gload16(gA2 + (K0), &As[B][lA2]); gload16(gA3 + (K0), &As[B][lA3]); \
                        gload16(gB0 + (K0), &Bs[B][lB0]); }
#define GCOMPUTE(B) { bf16x8 af[4], bfv[4]; \
  _Pragma("unroll") for (int mi = 0; mi < 4; ++mi) af[mi]  = *(const bf16x8*)&As[B][(wid * 64 + mi * 16 + lr) * 32 + lg * 8]; \
  _Pragma("unroll") for (int ni = 0; ni < 4; ++ni) bfv[ni] = *(const bf16x8*)&Bs[B][(ni * 16 + lr) * 32 + lg * 8]; \
  _Pragma("unroll") for (int mi = 0; mi < 4; ++mi) \
    _Pragma("unroll") for (int ni = 0; ni < 4; ++ni) \
      acc[mi][ni] = __builtin_amdgcn_mfma_f32_16x16x32_bf16(af[mi], bfv[ni], acc[mi][ni], 0, 0, 0); }

    GSTAGE(0, 0);
    __syncthreads();
#pragma unroll 1
    for (int tt = 0; tt < 16; tt += 2){
      if (tt + 1 < 16) GSTAGE(1, (tt + 1) * 32);
      GCOMPUTE(0);
      __syncthreads();
      if (tt + 2 < 16) GSTAGE(0, (tt + 2) * 32);
      GCOMPUTE(1);
      __syncthreads();
    }
#undef GSTAGE
#undef GCOMPUTE

#pragma unroll
    for (int mi = 0; mi < 4; ++mi)
#pragma unroll
      for (int ni = 0; ni < 4; ++ni)
#pragma unroll
        for (int rr = 0; rr < 4; ++rr){
          long gr = (long)g * 256 + wid * 64 + mi * 16 + lg * 4 + rr;
          int gn = ni * 16 + lr;
          if (gr < MPAD)
            gout[gr * GLD + gn] = (unsigned short)f2bf(acc[mi][ni][rr]);
        }
  } else if (blk < 444){
    // ===== tgemm: T = qbf @ wqk^T (f32 out), 128x128 tiles =====
    int L2 = blk - 316;
    int panel = L2 >> 5, nb = L2 & 31;
    int m0 = panel << 7, n0 = nb << 7;
    int wr = wid >> 1, wc = wid & 1;
    unsigned short* As[2] = { pool, pool + 4096 };
    unsigned short* Bs[2] = { pool + 8192, pool + 12288 };
    const unsigned short* gA0 = Aq + (long)(m0 + srow) * 512 + scol;
    const unsigned short* gA1 = gA0 + 64 * 512;
    const unsigned short* gB0 = Bw + (long)(n0 + srow) * 512 + scol;
    const unsigned short* gB1 = gB0 + 64 * 512;
    int lofs0 = (wid * 16) * 32;
    int lofs1 = (64 + wid * 16) * 32;

    f32x4 acc[4][4];
#pragma unroll
    for (int i = 0; i < 4; ++i)
#pragma unroll
      for (int j = 0; j < 4; ++j) acc[i][j] = (f32x4)0.f;

#define TSTAGE(B, K0) { gload16(gA0 + (K0), &As[B][lofs0]); gload16(gA1 + (K0), &As[B][lofs1]); \
                        gload16(gB0 + (K0), &Bs[B][lofs0]); gload16(gB1 + (K0), &Bs[B][lofs1]); }
#define TCOMPUTE(B) { bf16x8 af[4], bfv[4]; \
  _Pragma("unroll") for (int mi = 0; mi < 4; ++mi) af[mi]  = *(const bf16x8*)&As[B][(wr * 64 + mi * 16 + lr) * 32 + lg * 8]; \
  _Pragma("unroll") for (int ni = 0; ni < 4; ++ni) bfv[ni] = *(const bf16x8*)&Bs[B][(wc * 64 + ni * 16 + lr) * 32 + lg * 8]; \
  _Pragma("unroll") for (int mi = 0; mi < 4; ++mi) \
    _Pragma("unroll") for (int ni = 0; ni < 4; ++ni) \
      acc[mi][ni] = __builtin_amdgcn_mfma_f32_16x16x32_bf16(af[mi], bfv[ni], acc[mi][ni], 0, 0, 0); }

    TSTAGE(0, 0);
    __syncthreads();
#pragma unroll 1
    for (int tt = 0; tt < 16; tt += 2){
      if (tt + 1 < 16) TSTAGE(1, (tt + 1) * 32);
      TCOMPUTE(0);
      __syncthreads();
      if (tt + 2 < 16) TSTAGE(0, (tt + 2) * 32);
      TCOMPUTE(1);
      __syncthreads();
    }
#undef TSTAGE
#undef TCOMPUTE

#pragma unroll
    for (int mi = 0; mi < 4; ++mi)
#pragma unroll
      for (int ni = 0; ni < 4; ++ni)
#pragma unroll
        for (int rr = 0; rr < 4; ++rr){
          int gr = m0 + wr * 64 + mi * 16 + lg * 4 + rr;
          int gn = n0 + wc * 64 + ni * 16 + lr;
          T[(long)gr * TLD + gn] = acc[mi][ni][rr];
        }
  } else {
    // ===== W2 = sq_w @ skwT (f32), 4 waves x 2 rows = 8 rows/block =====
    int bx3 = blk - 444;           // 0..511
    int rt = bx3 & 63, nt2 = bx3 >> 6;
    int r0 = rt * 8 + wid * 2;
    int nn = nt2 * 64 + lane;
    const float* a0 = sq_w + (long)r0 * 512;
    const float* bp = skwT + nn;
    float acc0 = 0.f, acc1 = 0.f;
#pragma unroll 4
    for (int k = 0; k < 512; k += 4){
      float b0 = bp[(long)k * 512];
      float b1 = bp[(long)(k + 1) * 512];
      float b2 = bp[(long)(k + 2) * 512];
      float b3 = bp[(long)(k + 3) * 512];
      float4 a;
      a = *(const float4*)(a0 + k);
      acc0 += a.x * b0 + a.y * b1 + a.z * b2 + a.w * b3;
      a = *(const float4*)(a0 + 512 + k);
      acc1 += a.x * b0 + a.y * b1 + a.z * b2 + a.w * b3;
    }
    W2buf[(long)r0 * W2LD + nn]       = acc0;
    W2buf[(long)(r0 + 1) * W2LD + nn] = acc1;
  }
}

// ---------------- ustb: blocks [0,576) u_ext (2 rows/wave); [576,1525) stbeta ----------------
__global__ __launch_bounds__(256) void ustb_kernel(const float* __restrict__ queries,
                                                   const float* __restrict__ W2buf,
                                                   float* __restrict__ u_ext,
                                                   const float* __restrict__ summ,
                                                   const float* __restrict__ v2,
                                                   const float* __restrict__ gbuf,
                                                   float* __restrict__ summText,
                                                   float* __restrict__ betag){
  int blk = blockIdx.x;
  int t = threadIdx.x;
  if (blk < 576){
    int ax = blk & 63, ay = blk >> 6;
    int lane = t & 63, w = t >> 6;
    int r0 = ax * 8 + w * 2;
    int n  = ay * 64 + lane;
    const float* a0 = queries + (long)r0 * 512;
    const float* bp = W2buf + n;
    float acc0 = 0.f, acc1 = 0.f;
#pragma unroll 4
    for (int k = 0; k < 512; k += 4){
      float b0 = bp[(long)k * W2LD];
      float b1 = bp[(long)(k + 1) * W2LD];
      float b2 = bp[(long)(k + 2) * W2LD];
      float b3 = bp[(long)(k + 3) * W2LD];
      float4 a;
      a = *(const float4*)(a0 + k);
      acc0 += a.x * b0 + a.y * b1 + a.z * b2 + a.w * b3;
      a = *(const float4*)(a0 + 512 + k);
      acc1 += a.x * b0 + a.y * b1 + a.z * b2 + a.w * b3;
    }
    u_ext[(long)r0 * W2LD + n]       = acc0;
    u_ext[(long)(r0 + 1) * W2LD + n] = acc1;
  } else if (blk < 896){
    __shared__ float tile[64][65];
    int b2 = blk - 576;
    int b = b2 / 80; int rem = b2 % 80;
    int n0 = (rem / 8) * 64, e0 = (rem % 8) * 64;
    int c = t & 63, rbase = t >> 6;
#pragma unroll
    for (int j = 0; j < 16; ++j){
      int r = rbase + j * 4;
      int n = n0 + r;
      tile[r][c] = (n < NCHUNK) ? summ[((long)b * NCHUNK + n) * 512 + e0 + c] : 0.f;
    }
    __syncthreads();
#pragma unroll
    for (int j = 0; j < 16; ++j){
      int re = rbase + j * 4;
      summText[(long)b * STROWS * LGLD + (long)(e0 + re) * LGLD + n0 + c] = tile[c][re];
    }
  } else if (blk < 900){
    int b = blk - 896;
    for (int idx = t; idx < 8 * LGLD; idx += 256){
      int e = idx / LGLD, n = idx - e * LGLD;
      summText[(long)b * STROWS * LGLD + (long)(512 + e) * LGLD + n] = (e == 0) ? 1.f : 0.f;
    }
  } else {
    int bb = blk - 900;
    int w = t >> 6, lane = t & 63;
    int row = bb * 4 + w;
    const float* r = summ + (long)row * 512;
    float s = 0.f;
#pragma unroll
    for (int c = 0; c < 8; ++c) s += r[lane + 64 * c] * v2[lane + 64 * c];
    for (int d = 32; d >= 1; d >>= 1) s += __shfl_xor(s, d, 64);
    if (lane == 0){
      int b = row / NCHUNK, n = row % NCHUNK;
      betag[b * LGLD + n] = s + gbuf[0];
    }
  }
}

// ---------------- logits (NN form): 2 rows/wave, grid (16,10,NB) ----------------
__global__ __launch_bounds__(256) void logits_nn(const float* __restrict__ u_ext,
                                                 const float* __restrict__ summText,
                                                 const float* __restrict__ betag,
                                                 const float* __restrict__ chunkden,
                                                 float* __restrict__ logits){
  int b = blockIdx.z;
  int tid = threadIdx.x;
  int lane = tid & 63, w = tid >> 6;
  int r0 = blockIdx.x * 8 + w * 2;
  int n  = blockIdx.y * 64 + lane;
  const float* a0 = u_ext + ((long)b * QN + r0) * W2LD;
  const float* bp = summText + (long)b * STROWS * LGLD + n;
  float acc0 = 0.f, acc1 = 0.f;
#pragma unroll 4
  for (int k = 0; k < STROWS; k += 4){
    float b0 = bp[(long)k * LGLD];
    float b1 = bp[(long)(k + 1) * LGLD];
    float b2 = bp[(long)(k + 2) * LGLD];
    float b3 = bp[(long)(k + 3) * LGLD];
    float4 a;
    a = *(const float4*)(a0 + k);
    acc0 += a.x * b0 + a.y * b1 + a.z * b2 + a.w * b3;
    a = *(const float4*)(a0 + W2LD + k);
    acc1 += a.x * b0 + a.y * b1 + a.z * b2 + a.w * b3;
  }
  if (n < NCHUNK){
    float bet = betag[b * LGLD + n];
    bool dead = (chunkden[b * NCHUNK + n] <= 0.f);
    float v0 = (acc0 + bet) * LOGIT_SCALE;
    float v1 = (acc1 + bet) * LOGIT_SCALE;
    if (dead){ v0 = v1 = -FLT_MAX; }
    long base = ((long)b * QN + r0) * LGLD + n;
    logits[base]        = v0;
    logits[base + LGLD] = v1;
  }
}

// ---------------- top-8 + softmax weights, 4 waves per (b,i) row ----------------
__global__ __launch_bounds__(256) void topk_kernel(const float* __restrict__ logits,
                                                   int* __restrict__ topi_out,
                                                   float* __restrict__ wts_out){
  int row = blockIdx.x;
  __shared__ float lds[NCHUNK];
  __shared__ float wv[4];
  __shared__ int   wi[4];
  __shared__ float topv[TOPKK];
  __shared__ int   topi[TOPKK];
  int t = threadIdx.x;
  int lane = t & 63, w = t >> 6;
  for (int idx = t; idx < NCHUNK; idx += 256) lds[idx] = logits[(long)row * LGLD + idx];
  __syncthreads();
  for (int it = 0; it < TOPKK; ++it){
    float bv = -INFINITY; int bi = 0x7fffffff;
    for (int idx = t; idx < NCHUNK; idx += 256){
      float v = lds[idx];
      if (v > bv){ bv = v; bi = idx; }
    }
    for (int d = 32; d >= 1; d >>= 1){
      float ov = __shfl_xor(bv, d, 64);
      int   oi = __shfl_xor(bi, d, 64);
      if (ov > bv || (ov == bv && oi < bi)){ bv = ov; bi = oi; }
    }
    if (lane == 0){ wv[w] = bv; wi[w] = bi; }
    __syncthreads();
    if (t == 0){
      float fb = wv[0]; int fi = wi[0];
      for (int j = 1; j < 4; ++j){
        if (wv[j] > fb || (wv[j] == fb && wi[j] < fi)){ fb = wv[j]; fi = wi[j]; }
      }
      topv[it] = fb; topi[it] = fi; lds[fi] = -INFINITY;
    }
    __syncthreads();
  }
  if (t == 0){
    float m = topv[0];
    for (int r = 1; r < TOPKK; ++r) m = fmaxf(m, topv[r]);
    float e[TOPKK], s = 0.f;
    for (int r = 0; r < TOPKK; ++r){ e[r] = expf(topv[r] - m); s += e[r]; }
    for (int r = 0; r < TOPKK; ++r){
      wts_out[(long)row * TOPKK + r] = e[r] / s;
      topi_out[(long)row * TOPKK + r] = topi[r];
    }
  }
}

// ---------------- attention: A staged from abf (bf16), sim = T.A, G-fold out ----------------
#define ALDP 516   // attn A_lds row stride (bf16): 8B-aligned, 2-way-free for sim reads
__global__ __launch_bounds__(256) void attn5_kernel(const float* __restrict__ T,
                                                    const unsigned short* __restrict__ abf_all,
                                                    const unsigned short* __restrict__ g_all,
                                                    const int* __restrict__ topidx,
                                                    const float* __restrict__ wts,
                                                    const void* __restrict__ mask,
                                                    const int* __restrict__ flagp,
                                                    float* __restrict__ osc5){
  int bx = blockIdx.x;
  int bb = bx >> 10, rem = bx & 1023;
  int i = rem >> 3, k = rem & 7;
  const unsigned short* abf = abf_all + (size_t)bb * MPAD * 512;
  const unsigned short* gb  = g_all + (size_t)bb * MPAD * GLD;
  int t = threadIdx.x;
  __shared__ unsigned short A_lds[32 * ALDP];
  __shared__ float T_lds[TLD];
  __shared__ float red[4][5];
  int flag = *flagp;
  long sel = ((long)(bb * QN + i)) * TOPKK + k;
  int chunk = topidx[sel];
  float w8 = wts[sel];
  const float* Trow = T + (long)(bb * QN + i) * TLD;
  for (int idx = t; idx < 1024; idx += 256)
    *(float4*)&T_lds[idx * 4] = *(const float4*)&Trow[idx * 4];
  {
    int r = t >> 3, cb = (t & 7) * 64;
    const unsigned short* src = abf + (long)(chunk * CHUNK + r) * 512 + cb;
    unsigned short* dst = &A_lds[r * ALDP + cb];
#pragma unroll
    for (int j = 0; j < 8; ++j){
      bf16x8 a8 = *(const bf16x8*)(src + j * 8);
      bf16x4 lo = {a8[0], a8[1], a8[2], a8[3]};
      bf16x4 hi = {a8[4], a8[5], a8[6], a8[7]};
      *(bf16x4*)(dst + j * 8)     = lo;
      *(bf16x4*)(dst + j * 8 + 4) = hi;
    }
  }
  __syncthreads();
  int h = t >> 5, c = t & 31;
  const unsigned short* arow = &A_lds[c * ALDP];
  const float* tp = &T_lds[h * 512];
  float s = 0.f;
#pragma unroll 4
  for (int e8 = 0; e8 < 64; ++e8){
    bf16x4 alo = *(const bf16x4*)(arow + e8 * 8);
    bf16x4 ahi = *(const bf16x4*)(arow + e8 * 8 + 4);
    float4 ta = *(const float4*)(tp + e8 * 8);
    float4 tb = *(const float4*)(tp + e8 * 8 + 4);
    s += bf2f((unsigned short)alo[0]) * ta.x + bf2f((unsigned short)alo[1]) * ta.y
       + bf2f((unsigned short)alo[2]) * ta.z + bf2f((unsigned short)alo[3]) * ta.w
       + bf2f((unsigned short)ahi[0]) * tb.x + bf2f((unsigned short)ahi[1]) * tb.y
       + bf2f((unsigned short)ahi[2]) * tb.z + bf2f((unsigned short)ahi[3]) * tb.w;
  }
  bool mv = mask_at(mask, flag, (long)bb * NMEM + (long)chunk * CHUNK + c);
  if (!mv) s = -FLT_MAX;
  float m = s;
  for (int d = 16; d >= 1; d >>= 1) m = fmaxf(m, __shfl_xor(m, d, 32));
  float p = expf(s - m);
  float su = p;
  for (int d = 16; d >= 1; d >>= 1) su += __shfl_xor(su, d, 32);
  float att = p / su;
  const unsigned short* grow = gb + (long)(chunk * CHUNK + c) * GLD + h * 5;
  float p0 = att * bf2f(grow[0]);
  float p1 = att * bf2f(grow[1]);
  float p2 = att * bf2f(grow[2]);
  float p3 = att * bf2f(grow[3]);
  float p4 = att * bf2f(grow[4]);
#pragma unroll
  for (int d = 32; d >= 1; d >>= 1){
    p0 += __shfl_xor(p0, d, 64);
    p1 += __shfl_xor(p1, d, 64);
    p2 += __shfl_xor(p2, d, 64);
    p3 += __shfl_xor(p3, d, 64);
    p4 += __shfl_xor(p4, d, 64);
  }
  int w = t >> 6, lane = t & 63;
  if (lane == 0){
    red[w][0] = p0; red[w][1] = p1; red[w][2] = p2; red[w][3] = p3; red[w][4] = p4;
  }
  __syncthreads();
  if (t < 5){
    float tot = red[0][t] + red[1][t] + red[2][t] + red[3][t];
    osc5[sel * 8 + t] = w8 * tot;
  }
}

// ---------------- final5 ----------------
__global__ __launch_bounds__(64) void final5_kernel(const float* __restrict__ osc5,
                                                    const float* __restrict__ bfold,
                                                    float* __restrict__ out){
  int bi = blockIdx.x;
  int t = threadIdx.x;
  if (t < 5){
    float a = bfold[t];
#pragma unroll
    for (int k = 0; k < TOPKK; ++k) a += osc5[((long)bi * TOPKK + k) * 8 + t];
    out[bi * 5 + t] = a;
  }
}

extern "C" void kernel_launch(void* const* d_in, const int* in_sizes, int n_in,
                              void* d_out, int out_size, void* d_ws, size_t ws_size,
                              hipStream_t stream) {
  const float* queries  = (const float*)d_in[1];
  const float* memories = (const float*)d_in[2];
  const void*  mask     = d_in[3];
  const float* sq_w = (const float*)d_in[10];
  const float* sq_b = (const float*)d_in[11];
  const float* sk_w = (const float*)d_in[12];
  const float* sk_b = (const float*)d_in[13];
  const float* q_w  = (const float*)d_in[14];
  const float* kv_w = (const float*)d_in[15];
  const float* out_w = (const float*)d_in[16];
  const float* out_b = (const float*)d_in[17];
  const float* fc2_w = (const float*)d_in[18];
  const float* fc2_b = (const float*)d_in[19];
  float* out = (float*)d_out;

  char* ws = (char*)d_ws;
  size_t off = 0;
  auto alloc = [&](size_t bytes){ size_t o = off; off += (bytes + 511) & ~(size_t)511; return o; };
  size_t o_sum  = alloc(5120000);
  size_t o_den  = alloc(10240);
  size_t o_pos  = alloc(65536);
  size_t o_bf   = alloc(512);
  size_t o_ti   = alloc(16384);
  size_t o_wt   = alloc(16384);
  size_t o_flag = alloc(512);
  size_t o_w2   = alloc(1179648);
  size_t o_uex  = alloc(1179648);
  size_t o_st   = alloc(5324800);
  size_t o_bg   = alloc(10240);
  size_t o_v2   = alloc(2048);
  size_t o_gm   = alloc(512);
  size_t o_lg   = alloc(1310720);
  size_t o_osc5 = alloc(131072);
  size_t o_skt  = alloc(1048576);
  size_t o_qbf  = alloc(524288);
  size_t o_wqk  = alloc(4194304);
  size_t o_T    = alloc((size_t)NB * QN * TLD * 4);
  size_t o_pb   = alloc(65536);
  size_t o_abf  = alloc((size_t)NB * MPAD * 512 * 2);   // 82,313,216
  size_t o_g    = alloc((size_t)NB * MPAD * GLD * 2);   // 10,289,152

  float* summ  = (float*)(ws + o_sum);
  float* den   = (float*)(ws + o_den);
  float* pos   = (float*)(ws + o_pos);
  float* bfold = (float*)(ws + o_bf);
  int*   ti    = (int*)  (ws + o_ti);
  float* wt    = (float*)(ws + o_wt);
  int*   flagp = (int*)  (ws + o_flag);
  float* W2buf = (float*)(ws + o_w2);
  float* u_ext = (float*)(ws + o_uex);
  float* summText = (float*)(ws + o_st);
  float* betag = (float*)(ws + o_bg);
  float* v2    = (float*)(ws + o_v2);
  float* gbuf  = (float*)(ws + o_gm);
  float* logit = (float*)(ws + o_lg);
  float* osc5  = (float*)(ws + o_osc5);
  float* skwT  = (float*)(ws + o_skt);
  unsigned short* qb   = (unsigned short*)(ws + o_qbf);
  unsigned short* wqk  = (unsigned short*)(ws + o_wqk);
  float* Tbuf  = (float*)(ws + o_T);
  unsigned short* PB   = (unsigned short*)(ws + o_pb);
  unsigned short* abf  = (unsigned short*)(ws + o_abf);
  unsigned short* gall = (unsigned short*)(ws + o_g);

  bigsetup_kernel<<<dim3(710), dim3(256), 0, stream>>>(
      sk_w, mask, out_w, out_b, fc2_w, fc2_b, sq_w, sq_b, sk_b, q_w, kv_w, queries,
      skwT, pos, flagp, bfold, W2buf, v2, gbuf, wqk, qb, PB);

  prepsum_kernel<<<dim3(NCHUNK + 1, NB), dim3(512), 0, stream>>>(
      memories, pos, mask, flagp, abf, summ, den);

  gt_gemm<<<dim3(956), dim3(256), 0, stream>>>(
      abf, PB, gall, qb, wqk, Tbuf, sq_w, skwT, W2buf);

  ustb_kernel<<<dim3(1525), dim3(256), 0, stream>>>(
      queries, W2buf, u_ext, summ, v2, gbuf, summText, betag);
  logits_nn<<<dim3(16, 10, NB), dim3(256), 0, stream>>>(u_ext, summText, betag, den, logit);
  topk_kernel<<<dim3(NB * QN), dim3(256), 0, stream>>>(logit, ti, wt);

  attn5_kernel<<<dim3(NB * QN * TOPKK), dim3(256), 0, stream>>>(
      Tbuf, abf, gall, ti, wt, mask, flagp, osc5);
  final5_kernel<<<dim3(NB * QN), dim3(64), 0, stream>>>(osc5, bfold, out);
}